// Round 3
// baseline (450.114 us; speedup 1.0000x reference)
//
#include <hip/hip_runtime.h>
#include <hip/hip_bf16.h>

#define SLOPE 0.1f

// ---- ws float-index layout (int flag at float idx 0, int counter at idx 1) ----
#define OFF_QW    1816    // 30   q_weights (softmax)
#define OFF_QNI   1846    // 30   1/||question_embeds[q]||
#define OFF_QNS   1876    // 30   1/||q_conv[q]||
#define OFF_B1    4606    // 30
#define OFF_B2    7336    // 30
#define OFF_LQ1W  7366    // 48
#define OFF_LQ1B  7414    // 8
#define OFF_LQ2W  7422    // 8
#define OFF_LQ2B  7430    // 1
#define OFF_SOW   7431    // 4
#define OFF_SOB   7435    // 1
#define OFF_FLW   7436    // 5
#define OFF_FLB   7441    // 1
// ---- bf16 (u16-index) region, starts at byte 32768 ----
#define U16_QEA   16384   // 32 rows x 32  (A-operand QE, zeros at d>=30, q>=30)
#define U16_QCA   17408   // 32 rows x 32  (A-operand QC)
#define U16_WB1   18432   // 32 rows x 96  (B-operand conv1 W[o][kk], kk=k*30+i)
#define U16_WB2   21504   // 32 rows x 96

typedef __attribute__((ext_vector_type(8))) __bf16 bf16x8;
typedef __attribute__((ext_vector_type(4))) float f32x4;

union Frag { uint4 u4; uint u[4]; bf16x8 v; };

__device__ __forceinline__ float bf2f(ushort h) {
    union { uint u; float f; } c; c.u = ((uint)h) << 16; return c.f;
}
__device__ __forceinline__ ushort f2bf(float f) {   // RNE, finite inputs
    union { float f; uint u; } c; c.f = f;
    uint u = c.u;
    return (ushort)((u + 0x7FFFu + ((u >> 16) & 1u)) >> 16);
}
__device__ __forceinline__ float ldx(const void* p, long i, int bf) {
    if (bf) return bf2f(((const ushort*)p)[i]);
    return ((const float*)p)[i];
}
__device__ __forceinline__ void top5_insert(float v, float& t0, float& t1,
                                            float& t2, float& t3, float& t4) {
    bool b0 = v > t0, b1 = v > t1, b2 = v > t2, b3 = v > t3, b4 = v > t4;
    float n0 = b0 ? v  : t0;
    float n1 = b0 ? t0 : (b1 ? v : t1);
    float n2 = b1 ? t1 : (b2 ? v : t2);
    float n3 = b2 ? t2 : (b3 ? v : t3);
    float n4 = b3 ? t3 : (b4 ? v : t4);
    t0 = n0; t1 = n1; t2 = n2; t3 = n3; t4 = n4;
}

// ---------------- kernel 1: detect + question path + operand repack ----------------
__global__ __launch_bounds__(256) void k_prep(
        const void* doc_in,
        const void* qe_in, const void* qidf_in,
        const void* w1_in, const void* b1_in,
        const void* w2_in, const void* b2_in,
        const void* qwW_in, const void* qwb_in,
        const void* lq1W_in, const void* lq1b_in,
        const void* lq2W_in, const void* lq2b_in,
        const void* soW_in, const void* sob_in,
        const void* flW_in, const void* flb_in,
        float* ws) {
    const int tid = threadIdx.x;
    __shared__ float QE[900], T1[900], QC[900], W[2700], IDF[32], LG[32];
    __shared__ int scnt;

    // ---- dtype detection: f32 mantissa words have wild bf16-exponent fields ----
    if (tid == 0) scnt = 0;
    __syncthreads();
    {
        const ushort* p = (const ushort*)doc_in;
        int local = 0;
        for (int i = tid; i < 4096; i += 256) {
            unsigned e = (p[i] >> 7) & 0xFFu;
            if (e != 0u && (e < 100u || e > 134u)) local++;
        }
        atomicAdd(&scnt, local);
    }
    __syncthreads();
    const int bf = (scnt > 200) ? 0 : 1;
    if (tid == 0) { ((int*)ws)[0] = bf; ((int*)ws)[1] = 0; }   // flag + done-counter

    if (tid < 30) { ws[OFF_B1 + tid] = ldx(b1_in, tid, bf);
                    ws[OFF_B2 + tid] = ldx(b2_in, tid, bf); }
    if (tid < 48) ws[OFF_LQ1W + tid] = ldx(lq1W_in, tid, bf);
    if (tid < 8)  { ws[OFF_LQ1B + tid] = ldx(lq1b_in, tid, bf);
                    ws[OFF_LQ2W + tid] = ldx(lq2W_in, tid, bf); }
    if (tid < 4)  ws[OFF_SOW + tid] = ldx(soW_in, tid, bf);
    if (tid < 5)  ws[OFF_FLW + tid] = ldx(flW_in, tid, bf);
    if (tid == 0) { ws[OFF_LQ2B] = ldx(lq2b_in, 0, bf);
                    ws[OFF_SOB]  = ldx(sob_in, 0, bf);
                    ws[OFF_FLB]  = ldx(flb_in, 0, bf); }

    for (int i = tid; i < 900; i += 256) QE[i] = ldx(qe_in, i, bf);
    if (tid < 30) IDF[tid] = ldx(qidf_in, tid, bf);
    for (int i = tid; i < 2700; i += 256) W[i] = ldx(w1_in, i, bf);
    __syncthreads();

    for (int idx = tid; idx < 900; idx += 256) {
        int s = idx / 30, o = idx % 30;
        float acc = ldx(b1_in, o, bf);
        for (int k = 0; k < 3; ++k) {
            int t = s + k - 1;
            if (t < 0 || t >= 30) continue;
            for (int i = 0; i < 30; ++i) acc += QE[t*30 + i] * W[o*90 + i*3 + k];
        }
        acc = acc >= 0.f ? acc : SLOPE * acc;
        T1[idx] = acc + QE[idx];
    }
    __syncthreads();
    for (int i = tid; i < 2700; i += 256) W[i] = ldx(w2_in, i, bf);
    __syncthreads();
    for (int idx = tid; idx < 900; idx += 256) {
        int s = idx / 30, o = idx % 30;
        float acc = ldx(b2_in, o, bf);
        for (int k = 0; k < 3; ++k) {
            int t = s + k - 1;
            if (t < 0 || t >= 30) continue;
            for (int i = 0; i < 30; ++i) acc += T1[t*30 + i] * W[o*90 + i*3 + k];
        }
        acc = acc >= 0.f ? acc : SLOPE * acc;
        QC[idx] = acc + T1[idx];
    }
    __syncthreads();

    if (tid < 30) {
        float s1 = 0.f, s2 = 0.f;
        for (int d = 0; d < 30; ++d) {
            float a = QE[tid*30 + d]; s1 += a*a;
            float b = QC[tid*30 + d]; s2 += b*b;
        }
        ws[OFF_QNI + tid] = 1.0f / sqrtf(s1);
        ws[OFF_QNS + tid] = 1.0f / sqrtf(s2);
        float z = ldx(qwb_in, 0, bf);
        for (int d = 0; d < 30; ++d) z += QC[tid*30 + d] * ldx(qwW_in, d, bf);
        z += IDF[tid] * ldx(qwW_in, 30, bf);
        LG[tid] = z;
    }
    __syncthreads();
    if (tid == 0) {
        float m = -1e30f;
        for (int q = 0; q < 30; ++q) m = fmaxf(m, LG[q]);
        float sum = 0.f, e[30];
        for (int q = 0; q < 30; ++q) { e[q] = expf(LG[q] - m); sum += e[q]; }
        for (int q = 0; q < 30; ++q) ws[OFF_QW + q] = e[q] / sum;
    }

    // ---- repack A-operands (QE, QC) and B-operands (conv weights) to bf16 ----
    ushort* wsu = (ushort*)ws;
    for (int i = tid; i < 1024; i += 256) {
        int q = i >> 5, d = i & 31;
        float ve = (q < 30 && d < 30) ? QE[q*30 + d] : 0.f;
        float vc = (q < 30 && d < 30) ? QC[q*30 + d] : 0.f;
        wsu[U16_QEA + i] = f2bf(ve);
        wsu[U16_QCA + i] = f2bf(vc);
    }
    for (int i = tid; i < 3072; i += 256) {
        int o = i / 96, kk = i % 96;
        float v1 = 0.f, v2 = 0.f;
        if (o < 30 && kk < 90) {
            int ii = kk % 30, k = kk / 30;
            v1 = ldx(w1_in, o*90 + ii*3 + k, bf);
            v2 = ldx(w2_in, o*90 + ii*3 + k, bf);
        }
        wsu[U16_WB1 + i] = f2bf(v1);
        wsu[U16_WB2 + i] = f2bf(v2);
    }
}

// ---------------- MFMA tile helpers ----------------
// conv GEMM: M=s(100,7 tiles), N=o(30,2 tiles), K=96(3 steps).
// src flat bf16 stride 30, 103 rows (row 0 and rows 101,102 zero). A[s][kk]=src[s*30+kk].
__device__ __forceinline__ void conv_tile_rw(const uint* src32, uint* dst32, const uint4* wb,
                                             const float* bias, int t, int l15, int quad) {
    const ushort* srcU = (const ushort*)src32;
    ushort* dstU = (ushort*)dst32;
    int mt = t >> 1, nt = t & 1;
    int sa = mt * 16 + l15;
    f32x4 acc = {0.f, 0.f, 0.f, 0.f};
    Frag a, b;
    for (int k = 0; k < 3; ++k) {
        if (sa < 100) {
            int base = sa * 15 + k * 16 + quad * 4;
            a.u[0] = src32[base];     a.u[1] = src32[base + 1];
            a.u[2] = src32[base + 2]; a.u[3] = src32[base + 3];
        } else { a.u[0] = a.u[1] = a.u[2] = a.u[3] = 0u; }
        b.u4 = wb[(nt * 16 + l15) * 12 + k * 4 + quad];
        acc = __builtin_amdgcn_mfma_f32_16x16x32_bf16(a.v, b.v, acc, 0, 0, 0);
    }
    int o = nt * 16 + l15;
    if (o < 30) {
        float bo = bias[o];
        for (int r = 0; r < 4; ++r) {
            int s = mt * 16 + quad * 4 + r;
            if (s < 100) {
                float v = acc[r] + bo;
                v = v >= 0.f ? v : SLOPE * v;
                v += bf2f(srcU[(s + 1) * 30 + o]);
                dstU[(s + 1) * 30 + o] = f2bf(v);
            }
        }
    }
}

// sim GEMM: M=q(30,2 tiles), N=s(100,7 tiles), K=32(1 step).
__device__ __forceinline__ void sim_tile(const uint4* qa, const uint* src32, float* SIMb,
                                         const float* invq, const float* INVX,
                                         int t, int l15, int quad) {
    int mt = t / 7, nt = t % 7;
    Frag a, b;
    a.u4 = qa[(mt * 16 + l15) * 4 + quad];
    int s = nt * 16 + l15;
    if (s < 100) {
        int base = (s + 1) * 15 + quad * 4;
        b.u[0] = src32[base];     b.u[1] = src32[base + 1];
        b.u[2] = src32[base + 2]; b.u[3] = src32[base + 3];
    } else { b.u[0] = b.u[1] = b.u[2] = b.u[3] = 0u; }
    f32x4 acc = {0.f, 0.f, 0.f, 0.f};
    acc = __builtin_amdgcn_mfma_f32_16x16x32_bf16(a.v, b.v, acc, 0, 0, 0);
    if (s < 100) {
        float ix = INVX[s];
        for (int r = 0; r < 4; ++r) {
            int q = mt * 16 + quad * 4 + r;
            if (q < 30) SIMb[q * 101 + s] = acc[r] * invq[q] * ix;
        }
    }
}

// ---------------- kernel 2: per-sentence fused MFMA pipeline + doc head ----------------
__global__ __launch_bounds__(256) void k_main(const void* doc_in, const void* gaf_in,
                                              const void* docgaf_in, void* out, float* ws) {
    const int n = blockIdx.x;
    const int tid = threadIdx.x;
    const int bf = ((const int*)ws)[0];
    const int lane = tid & 63;
    const int wid = tid >> 6;
    const int l15 = lane & 15;
    const int quad = lane >> 4;

    __shared__ uint XA32[1546];     // X flat bf16: 103 rows x 30 (rows 0,101,102 zero)
    __shared__ uint XB32[1546];     // conv1 output, same layout
    __shared__ float SIM[3030];     // [30][101]
    __shared__ float INVX[100];
    __shared__ float FE[30][6];
    __shared__ int lastflag;

    ushort* XAu = (ushort*)XA32;
    const ushort* wsu = (const ushort*)ws;
    const uint4* qeA = (const uint4*)(wsu + U16_QEA);
    const uint4* qcA = (const uint4*)(wsu + U16_QCA);
    const uint4* wb1 = (const uint4*)(wsu + U16_WB1);
    const uint4* wb2 = (const uint4*)(wsu + U16_WB2);

    const int prow = tid >> 3;          // pooling: 8 lanes per q-row
    const int psub = tid & 7;

    // zero pad rows (dwords [0,15) and [1515,1546) in both buffers)
    for (int i = tid; i < 15; i += 256) { XA32[i] = 0u; XB32[i] = 0u; }
    for (int i = 1515 + tid; i < 1546; i += 256) { XA32[i] = 0u; XB32[i] = 0u; }
    // load sentence into XA rows 1..100
    if (bf) {
        const uint* g = (const uint*)((const ushort*)doc_in + (size_t)n * 3000);
        for (int i = tid; i < 1500; i += 256) XA32[15 + i] = g[i];
    } else {
        const float* p = (const float*)doc_in + (size_t)n * 3000;
        for (int i = tid; i < 3000; i += 256) XAu[30 + i] = f2bf(p[i]);
    }
    __syncthreads();

    // inverse row norms of X
    if (tid < 100) {
        const uint* r = XA32 + (tid + 1) * 15;
        float s = 0.f;
        for (int i = 0; i < 15; ++i) {
            uint u = r[i];
            float lo = __uint_as_float(u << 16);
            float hi = __uint_as_float(u & 0xFFFF0000u);
            s += lo * lo + hi * hi;
        }
        INVX[tid] = 1.f / sqrtf(s);
    }
    __syncthreads();

    // sim_insens
    for (int t = wid; t < 14; t += 4)
        sim_tile(qeA, XA32, SIM, ws + OFF_QNI, INVX, t, l15, quad);
    __syncthreads();

    // pool insens (+one-hot) across all 256 threads
    {
        float t0=-1e30f, t1=-1e30f, t2=-1e30f, t3=-1e30f, t4=-1e30f;
        int cnt = 0;
        if (prow < 30) {
            const float* r = SIM + prow * 101 + psub * 13;
            int ne = (psub == 7) ? 9 : 13;
            for (int i = 0; i < ne; ++i) {
                float v = r[i];
                cnt += (v > 0.999f) ? 1 : 0;
                top5_insert(v, t0, t1, t2, t3, t4);
            }
        }
        for (int d = 1; d < 8; d <<= 1) {
            float p0 = __shfl_xor(t0, d), p1 = __shfl_xor(t1, d), p2 = __shfl_xor(t2, d);
            float p3 = __shfl_xor(t3, d), p4 = __shfl_xor(t4, d);
            cnt += __shfl_xor(cnt, d);
            top5_insert(p0, t0, t1, t2, t3, t4);
            top5_insert(p1, t0, t1, t2, t3, t4);
            top5_insert(p2, t0, t1, t2, t3, t4);
            top5_insert(p3, t0, t1, t2, t3, t4);
            top5_insert(p4, t0, t1, t2, t3, t4);
        }
        if (prow < 30 && psub == 0) {
            FE[prow][0] = cnt > 0 ? 1.f : 0.f;
            FE[prow][1] = (float)(cnt > 5 ? 5 : cnt) * 0.2f;
            FE[prow][2] = t0;
            FE[prow][3] = (t0 + t1 + t2 + t3 + t4) * 0.2f;
        }
    }
    __syncthreads();

    // conv1 XA->XB
    for (int t = wid; t < 14; t += 4)
        conv_tile_rw(XA32, XB32, wb1, ws + OFF_B1, t, l15, quad);
    __syncthreads();

    // conv2 XB->XA
    for (int t = wid; t < 14; t += 4)
        conv_tile_rw(XB32, XA32, wb2, ws + OFF_B2, t, l15, quad);
    __syncthreads();

    // inverse row norms of conv_res
    if (tid < 100) {
        const uint* r = XA32 + (tid + 1) * 15;
        float s = 0.f;
        for (int i = 0; i < 15; ++i) {
            uint u = r[i];
            float lo = __uint_as_float(u << 16);
            float hi = __uint_as_float(u & 0xFFFF0000u);
            s += lo * lo + hi * hi;
        }
        INVX[tid] = 1.f / sqrtf(s);
    }
    __syncthreads();

    // sim_sens
    for (int t = wid; t < 14; t += 4)
        sim_tile(qcA, XA32, SIM, ws + OFF_QNS, INVX, t, l15, quad);
    __syncthreads();

    // pool sens across all 256 threads
    {
        float t0=-1e30f, t1=-1e30f, t2=-1e30f, t3=-1e30f, t4=-1e30f;
        if (prow < 30) {
            const float* r = SIM + prow * 101 + psub * 13;
            int ne = (psub == 7) ? 9 : 13;
            for (int i = 0; i < ne; ++i) top5_insert(r[i], t0, t1, t2, t3, t4);
        }
        for (int d = 1; d < 8; d <<= 1) {
            float p0 = __shfl_xor(t0, d), p1 = __shfl_xor(t1, d), p2 = __shfl_xor(t2, d);
            float p3 = __shfl_xor(t3, d), p4 = __shfl_xor(t4, d);
            top5_insert(p0, t0, t1, t2, t3, t4);
            top5_insert(p1, t0, t1, t2, t3, t4);
            top5_insert(p2, t0, t1, t2, t3, t4);
            top5_insert(p3, t0, t1, t2, t3, t4);
            top5_insert(p4, t0, t1, t2, t3, t4);
        }
        if (prow < 30 && psub == 0) {
            FE[prow][4] = t0;
            FE[prow][5] = (t0 + t1 + t2 + t3 + t4) * 0.2f;
        }
    }
    __syncthreads();

    // wave0: per-q MLP, butterfly-sum, score write
    if (wid == 0) {
        float val = 0.f;
        if (lane < 30) {
            float lo = ws[OFF_LQ2B];
            for (int j = 0; j < 8; ++j) {
                float h = ws[OFF_LQ1B + j];
                for (int f = 0; f < 6; ++f) h += FE[lane][f] * ws[OFF_LQ1W + j*6 + f];
                h = h >= 0.f ? h : SLOPE * h;
                lo += h * ws[OFF_LQ2W + j];
            }
            val = lo * ws[OFF_QW + lane];
        }
        for (int d = 32; d >= 1; d >>= 1) val += __shfl_xor(val, d);
        if (lane == 0) {
            float emit = val * (1.f / 30.f);
            float z = ws[OFF_SOB];
            z += ldx(gaf_in, (long)n*3 + 0, bf) * ws[OFF_SOW + 0];
            z += ldx(gaf_in, (long)n*3 + 1, bf) * ws[OFF_SOW + 1];
            z += ldx(gaf_in, (long)n*3 + 2, bf) * ws[OFF_SOW + 2];
            z += emit * ws[OFF_SOW + 3];
            float sc = 1.f / (1.f + expf(-z));
            if (bf) ((__hip_bfloat16*)out)[1 + n] = __float2bfloat16(sc);
            else    ((float*)out)[1 + n] = sc;
        }
    }

    // ---- last-block-done: doc-level head ----
    __threadfence();
    if (tid == 0) {
        int t = atomicAdd((int*)ws + 1, 1);
        lastflag = (t == 3999) ? 1 : 0;
    }
    __syncthreads();
    if (lastflag) {
        __threadfence();
        float* RED = SIM;   // reuse
        float m = -1e30f;
        for (int i = tid; i < 4000; i += 256) {
            float v = bf ? __bfloat162float(((const __hip_bfloat16*)out)[1 + i])
                         : ((const float*)out)[1 + i];
            m = fmaxf(m, v);
        }
        RED[tid] = m;
        __syncthreads();
        for (int off = 128; off > 0; off >>= 1) {
            if (tid < off) RED[tid] = fmaxf(RED[tid], RED[tid + off]);
            __syncthreads();
        }
        if (tid == 0) {
            float f = ws[OFF_FLB] + RED[0] * ws[OFF_FLW + 0];
            for (int i = 0; i < 4; ++i) f += ldx(docgaf_in, i, bf) * ws[OFF_FLW + 1 + i];
            if (bf) ((__hip_bfloat16*)out)[0] = __float2bfloat16(f);
            else    ((float*)out)[0] = f;
        }
    }
}

extern "C" void kernel_launch(void* const* d_in, const int* in_sizes, int n_in,
                              void* d_out, int out_size, void* d_ws, size_t ws_size,
                              hipStream_t stream) {
    float* ws = (float*)d_ws;
    k_prep<<<1, 256, 0, stream>>>(d_in[0], d_in[2], d_in[3], d_in[5], d_in[6], d_in[7], d_in[8],
                                  d_in[9], d_in[10], d_in[11], d_in[12], d_in[13], d_in[14],
                                  d_in[15], d_in[16], d_in[17], d_in[18], ws);
    k_main<<<4000, 256, 0, stream>>>(d_in[0], d_in[1], d_in[4], d_out, ws);
}

// Round 4
// 256.957 us; speedup vs baseline: 1.7517x; 1.7517x over previous
//
#include <hip/hip_runtime.h>
#include <hip/hip_bf16.h>

#define SLOPE 0.1f

// ---- ws int-index layout: [0]=bf flag, [1]=done counter, [2]=score max bits ----
// ---- ws float-index layout ----
#define OFF_QW    1816    // 30   q_weights (softmax)
#define OFF_QNI   1846    // 30   1/||question_embeds[q]||
#define OFF_QNS   1876    // 30   1/||q_conv[q]||
#define OFF_B1    4606    // 30
#define OFF_B2    7336    // 30
#define OFF_LQ1W  7366    // 48
#define OFF_LQ1B  7414    // 8
#define OFF_LQ2W  7422    // 8
#define OFF_LQ2B  7430    // 1
#define OFF_SOW   7431    // 4
#define OFF_SOB   7435    // 1
#define OFF_FLW   7436    // 5
#define OFF_FLB   7441    // 1
// ---- bf16 (u16-index) region, starts at byte 32768 ----
#define U16_QEA   16384   // 32 rows x 32  (A-operand QE, zeros at d>=30, q>=30)
#define U16_QCA   17408   // 32 rows x 32  (A-operand QC)
#define U16_WB1   18432   // 32 rows x 96  (B-operand conv1 W[o][kk], kk=k*30+i)
#define U16_WB2   21504   // 32 rows x 96

typedef __attribute__((ext_vector_type(8))) __bf16 bf16x8;
typedef __attribute__((ext_vector_type(4))) float f32x4;

union Frag { uint4 u4; uint u[4]; bf16x8 v; };

__device__ __forceinline__ float bf2f(ushort h) {
    union { uint u; float f; } c; c.u = ((uint)h) << 16; return c.f;
}
__device__ __forceinline__ ushort f2bf(float f) {   // RNE, finite inputs
    union { float f; uint u; } c; c.f = f;
    uint u = c.u;
    return (ushort)((u + 0x7FFFu + ((u >> 16) & 1u)) >> 16);
}
__device__ __forceinline__ float ldx(const void* p, long i, int bf) {
    if (bf) return bf2f(((const ushort*)p)[i]);
    return ((const float*)p)[i];
}
__device__ __forceinline__ void top5_insert(float v, float& t0, float& t1,
                                            float& t2, float& t3, float& t4) {
    bool b0 = v > t0, b1 = v > t1, b2 = v > t2, b3 = v > t3, b4 = v > t4;
    float n0 = b0 ? v  : t0;
    float n1 = b0 ? t0 : (b1 ? v : t1);
    float n2 = b1 ? t1 : (b2 ? v : t2);
    float n3 = b2 ? t2 : (b3 ? v : t3);
    float n4 = b3 ? t3 : (b4 ? v : t4);
    t0 = n0; t1 = n1; t2 = n2; t3 = n3; t4 = n4;
}
// dtype detection: f32 mantissa words carry wild bf16-exponent fields
__device__ __forceinline__ int detect_bf(const void* doc_in, int tid, int* scnt) {
    if (tid == 0) *scnt = 0;
    __syncthreads();
    const ushort* p = (const ushort*)doc_in;
    int local = 0;
    for (int i = tid; i < 4096; i += 256) {
        unsigned e = (p[i] >> 7) & 0xFFu;
        if (e != 0u && (e < 100u || e > 134u)) local++;
    }
    atomicAdd(scnt, local);
    __syncthreads();
    return (*scnt > 200) ? 0 : 1;
}

// ---------------- kernel 1 (3 blocks): detect + question path + repack ----------------
__global__ __launch_bounds__(256) void k_prep(
        const void* doc_in,
        const void* qe_in, const void* qidf_in,
        const void* w1_in, const void* b1_in,
        const void* w2_in, const void* b2_in,
        const void* qwW_in, const void* qwb_in,
        const void* lq1W_in, const void* lq1b_in,
        const void* lq2W_in, const void* lq2b_in,
        const void* soW_in, const void* sob_in,
        const void* flW_in, const void* flb_in,
        float* ws) {
    const int tid = threadIdx.x;
    const int blk = blockIdx.x;
    __shared__ float QE[900], T1[900], QC[900], W[2700], IDF[32], LG[32];
    __shared__ int scnt;

    const int bf = detect_bf(doc_in, tid, &scnt);
    ushort* wsu = (ushort*)ws;

    if (blk == 1) {
        // small params + conv1 weight repack
        if (tid == 0) { ((int*)ws)[0] = bf; }  // also written here (idempotent)
        if (tid < 30) ws[OFF_B1 + tid] = ldx(b1_in, tid, bf);
        if (tid < 48) ws[OFF_LQ1W + tid] = ldx(lq1W_in, tid, bf);
        if (tid < 8)  { ws[OFF_LQ1B + tid] = ldx(lq1b_in, tid, bf);
                        ws[OFF_LQ2W + tid] = ldx(lq2W_in, tid, bf); }
        if (tid < 4)  ws[OFF_SOW + tid] = ldx(soW_in, tid, bf);
        if (tid < 5)  ws[OFF_FLW + tid] = ldx(flW_in, tid, bf);
        if (tid == 1) { ws[OFF_LQ2B] = ldx(lq2b_in, 0, bf);
                        ws[OFF_SOB]  = ldx(sob_in, 0, bf);
                        ws[OFF_FLB]  = ldx(flb_in, 0, bf); }
        for (int i = tid; i < 3072; i += 256) {
            int o = i / 96, kk = i % 96;
            float v1 = 0.f;
            if (o < 30 && kk < 90) {
                int ii = kk % 30, k = kk / 30;
                v1 = ldx(w1_in, (long)o*90 + ii*3 + k, bf);
            }
            wsu[U16_WB1 + i] = f2bf(v1);
        }
        return;
    }
    if (blk == 2) {
        if (tid < 30) ws[OFF_B2 + tid] = ldx(b2_in, tid, bf);
        for (int i = tid; i < 3072; i += 256) {
            int o = i / 96, kk = i % 96;
            float v2 = 0.f;
            if (o < 30 && kk < 90) {
                int ii = kk % 30, k = kk / 30;
                v2 = ldx(w2_in, (long)o*90 + ii*3 + k, bf);
            }
            wsu[U16_WB2 + i] = f2bf(v2);
        }
        return;
    }

    // ---- block 0: control words + question path ----
    if (tid == 0) { ((int*)ws)[0] = bf; ((int*)ws)[1] = 0; ((int*)ws)[2] = 0; }

    for (int i = tid; i < 900; i += 256) QE[i] = ldx(qe_in, i, bf);
    if (tid < 30) IDF[tid] = ldx(qidf_in, tid, bf);
    for (int i = tid; i < 2700; i += 256) W[i] = ldx(w1_in, i, bf);
    __syncthreads();

    for (int idx = tid; idx < 900; idx += 256) {
        int s = idx / 30, o = idx % 30;
        float acc = ldx(b1_in, o, bf);
        for (int k = 0; k < 3; ++k) {
            int t = s + k - 1;
            if (t < 0 || t >= 30) continue;
            for (int i = 0; i < 30; ++i) acc += QE[t*30 + i] * W[o*90 + i*3 + k];
        }
        acc = acc >= 0.f ? acc : SLOPE * acc;
        T1[idx] = acc + QE[idx];
    }
    __syncthreads();
    for (int i = tid; i < 2700; i += 256) W[i] = ldx(w2_in, i, bf);
    __syncthreads();
    for (int idx = tid; idx < 900; idx += 256) {
        int s = idx / 30, o = idx % 30;
        float acc = ldx(b2_in, o, bf);
        for (int k = 0; k < 3; ++k) {
            int t = s + k - 1;
            if (t < 0 || t >= 30) continue;
            for (int i = 0; i < 30; ++i) acc += T1[t*30 + i] * W[o*90 + i*3 + k];
        }
        acc = acc >= 0.f ? acc : SLOPE * acc;
        QC[idx] = acc + T1[idx];
    }
    __syncthreads();

    if (tid < 30) {
        float s1 = 0.f, s2 = 0.f;
        for (int d = 0; d < 30; ++d) {
            float a = QE[tid*30 + d]; s1 += a*a;
            float b = QC[tid*30 + d]; s2 += b*b;
        }
        ws[OFF_QNI + tid] = 1.0f / sqrtf(s1);
        ws[OFF_QNS + tid] = 1.0f / sqrtf(s2);
        float z = ldx(qwb_in, 0, bf);
        for (int d = 0; d < 30; ++d) z += QC[tid*30 + d] * ldx(qwW_in, d, bf);
        z += IDF[tid] * ldx(qwW_in, 30, bf);
        LG[tid] = z;
    }
    __syncthreads();
    if (tid == 0) {
        float m = -1e30f;
        for (int q = 0; q < 30; ++q) m = fmaxf(m, LG[q]);
        float sum = 0.f, e[30];
        for (int q = 0; q < 30; ++q) { e[q] = expf(LG[q] - m); sum += e[q]; }
        for (int q = 0; q < 30; ++q) ws[OFF_QW + q] = e[q] / sum;
    }
    for (int i = tid; i < 1024; i += 256) {
        int q = i >> 5, d = i & 31;
        float ve = (q < 30 && d < 30) ? QE[q*30 + d] : 0.f;
        float vc = (q < 30 && d < 30) ? QC[q*30 + d] : 0.f;
        wsu[U16_QEA + i] = f2bf(ve);
        wsu[U16_QCA + i] = f2bf(vc);
    }
}

// ---------------- MFMA tile helpers ----------------
// conv GEMM: M=s(100,7 tiles), N=o(30,2 tiles), K=96(3 steps).
// src flat bf16 stride 30, 103 rows (row 0 and rows 101,102 zero). A[s][kk]=src[s*30+kk].
__device__ __forceinline__ void conv_tile_rw(const uint* src32, uint* dst32, const uint4* wb,
                                             const float* bias, int t, int l15, int quad) {
    const ushort* srcU = (const ushort*)src32;
    ushort* dstU = (ushort*)dst32;
    int mt = t >> 1, nt = t & 1;
    int sa = mt * 16 + l15;
    f32x4 acc = {0.f, 0.f, 0.f, 0.f};
    Frag a, b;
    for (int k = 0; k < 3; ++k) {
        if (sa < 100) {
            int base = sa * 15 + k * 16 + quad * 4;
            a.u[0] = src32[base];     a.u[1] = src32[base + 1];
            a.u[2] = src32[base + 2]; a.u[3] = src32[base + 3];
        } else { a.u[0] = a.u[1] = a.u[2] = a.u[3] = 0u; }
        b.u4 = wb[(nt * 16 + l15) * 12 + k * 4 + quad];
        acc = __builtin_amdgcn_mfma_f32_16x16x32_bf16(a.v, b.v, acc, 0, 0, 0);
    }
    int o = nt * 16 + l15;
    if (o < 30) {
        float bo = bias[o];
        for (int r = 0; r < 4; ++r) {
            int s = mt * 16 + quad * 4 + r;
            if (s < 100) {
                float v = acc[r] + bo;
                v = v >= 0.f ? v : SLOPE * v;
                v += bf2f(srcU[(s + 1) * 30 + o]);
                dstU[(s + 1) * 30 + o] = f2bf(v);
            }
        }
    }
}

// sim GEMM: M=q(30,2 tiles), N=s(100,7 tiles), K=32(1 step).
__device__ __forceinline__ void sim_tile(const uint4* qa, const uint* src32, float* SIMb,
                                         const float* invq, const float* INVX,
                                         int t, int l15, int quad) {
    int mt = t / 7, nt = t % 7;
    Frag a, b;
    a.u4 = qa[(mt * 16 + l15) * 4 + quad];
    int s = nt * 16 + l15;
    if (s < 100) {
        int base = (s + 1) * 15 + quad * 4;
        b.u[0] = src32[base];     b.u[1] = src32[base + 1];
        b.u[2] = src32[base + 2]; b.u[3] = src32[base + 3];
    } else { b.u[0] = b.u[1] = b.u[2] = b.u[3] = 0u; }
    f32x4 acc = {0.f, 0.f, 0.f, 0.f};
    acc = __builtin_amdgcn_mfma_f32_16x16x32_bf16(a.v, b.v, acc, 0, 0, 0);
    if (s < 100) {
        float ix = INVX[s];
        for (int r = 0; r < 4; ++r) {
            int q = mt * 16 + quad * 4 + r;
            if (q < 30) SIMb[q * 101 + s] = acc[r] * invq[q] * ix;
        }
    }
}

// ---------------- kernel 2: per-sentence fused MFMA pipeline + atomic doc head ----------------
__global__ __launch_bounds__(256) void k_main(const void* doc_in, const void* gaf_in,
                                              const void* docgaf_in, void* out, float* ws) {
    const int n = blockIdx.x;
    const int tid = threadIdx.x;
    const int bf = ((const int*)ws)[0];
    const int lane = tid & 63;
    const int wid = tid >> 6;
    const int l15 = lane & 15;
    const int quad = lane >> 4;

    __shared__ uint XA32[1546];     // X flat bf16: 103 rows x 30 (rows 0,101,102 zero)
    __shared__ uint XB32[1546];     // conv1 output, same layout
    __shared__ float SIM[3030];     // [30][101]
    __shared__ float INVX[100];
    __shared__ float FE[30][6];

    ushort* XAu = (ushort*)XA32;
    const ushort* wsu = (const ushort*)ws;
    const uint4* qeA = (const uint4*)(wsu + U16_QEA);
    const uint4* qcA = (const uint4*)(wsu + U16_QCA);
    const uint4* wb1 = (const uint4*)(wsu + U16_WB1);
    const uint4* wb2 = (const uint4*)(wsu + U16_WB2);

    const int prow = tid >> 3;          // pooling: 8 lanes per q-row
    const int psub = tid & 7;

    // zero pad rows (dwords [0,15) and [1515,1546) in both buffers)
    for (int i = tid; i < 15; i += 256) { XA32[i] = 0u; XB32[i] = 0u; }
    for (int i = 1515 + tid; i < 1546; i += 256) { XA32[i] = 0u; XB32[i] = 0u; }
    // load sentence into XA rows 1..100
    if (bf) {
        const uint* g = (const uint*)((const ushort*)doc_in + (size_t)n * 3000);
        for (int i = tid; i < 1500; i += 256) XA32[15 + i] = g[i];
    } else {
        const float* p = (const float*)doc_in + (size_t)n * 3000;
        for (int i = tid; i < 3000; i += 256) XAu[30 + i] = f2bf(p[i]);
    }
    __syncthreads();

    // inverse row norms of X
    if (tid < 100) {
        const uint* r = XA32 + (tid + 1) * 15;
        float s = 0.f;
        for (int i = 0; i < 15; ++i) {
            uint u = r[i];
            float lo = __uint_as_float(u << 16);
            float hi = __uint_as_float(u & 0xFFFF0000u);
            s += lo * lo + hi * hi;
        }
        INVX[tid] = 1.f / sqrtf(s);
    }
    __syncthreads();

    // sim_insens
    for (int t = wid; t < 14; t += 4)
        sim_tile(qeA, XA32, SIM, ws + OFF_QNI, INVX, t, l15, quad);
    __syncthreads();

    // pool insens (+one-hot) across all 256 threads
    {
        float t0=-1e30f, t1=-1e30f, t2=-1e30f, t3=-1e30f, t4=-1e30f;
        int cnt = 0;
        if (prow < 30) {
            const float* r = SIM + prow * 101 + psub * 13;
            int ne = (psub == 7) ? 9 : 13;
            for (int i = 0; i < ne; ++i) {
                float v = r[i];
                cnt += (v > 0.999f) ? 1 : 0;
                top5_insert(v, t0, t1, t2, t3, t4);
            }
        }
        for (int d = 1; d < 8; d <<= 1) {
            float p0 = __shfl_xor(t0, d), p1 = __shfl_xor(t1, d), p2 = __shfl_xor(t2, d);
            float p3 = __shfl_xor(t3, d), p4 = __shfl_xor(t4, d);
            cnt += __shfl_xor(cnt, d);
            top5_insert(p0, t0, t1, t2, t3, t4);
            top5_insert(p1, t0, t1, t2, t3, t4);
            top5_insert(p2, t0, t1, t2, t3, t4);
            top5_insert(p3, t0, t1, t2, t3, t4);
            top5_insert(p4, t0, t1, t2, t3, t4);
        }
        if (prow < 30 && psub == 0) {
            FE[prow][0] = cnt > 0 ? 1.f : 0.f;
            FE[prow][1] = (float)(cnt > 5 ? 5 : cnt) * 0.2f;
            FE[prow][2] = t0;
            FE[prow][3] = (t0 + t1 + t2 + t3 + t4) * 0.2f;
        }
    }
    __syncthreads();

    // conv1 XA->XB
    for (int t = wid; t < 14; t += 4)
        conv_tile_rw(XA32, XB32, wb1, ws + OFF_B1, t, l15, quad);
    __syncthreads();

    // conv2 XB->XA
    for (int t = wid; t < 14; t += 4)
        conv_tile_rw(XB32, XA32, wb2, ws + OFF_B2, t, l15, quad);
    __syncthreads();

    // inverse row norms of conv_res
    if (tid < 100) {
        const uint* r = XA32 + (tid + 1) * 15;
        float s = 0.f;
        for (int i = 0; i < 15; ++i) {
            uint u = r[i];
            float lo = __uint_as_float(u << 16);
            float hi = __uint_as_float(u & 0xFFFF0000u);
            s += lo * lo + hi * hi;
        }
        INVX[tid] = 1.f / sqrtf(s);
    }
    __syncthreads();

    // sim_sens
    for (int t = wid; t < 14; t += 4)
        sim_tile(qcA, XA32, SIM, ws + OFF_QNS, INVX, t, l15, quad);
    __syncthreads();

    // pool sens across all 256 threads
    {
        float t0=-1e30f, t1=-1e30f, t2=-1e30f, t3=-1e30f, t4=-1e30f;
        if (prow < 30) {
            const float* r = SIM + prow * 101 + psub * 13;
            int ne = (psub == 7) ? 9 : 13;
            for (int i = 0; i < ne; ++i) top5_insert(r[i], t0, t1, t2, t3, t4);
        }
        for (int d = 1; d < 8; d <<= 1) {
            float p0 = __shfl_xor(t0, d), p1 = __shfl_xor(t1, d), p2 = __shfl_xor(t2, d);
            float p3 = __shfl_xor(t3, d), p4 = __shfl_xor(t4, d);
            top5_insert(p0, t0, t1, t2, t3, t4);
            top5_insert(p1, t0, t1, t2, t3, t4);
            top5_insert(p2, t0, t1, t2, t3, t4);
            top5_insert(p3, t0, t1, t2, t3, t4);
            top5_insert(p4, t0, t1, t2, t3, t4);
        }
        if (prow < 30 && psub == 0) {
            FE[prow][4] = t0;
            FE[prow][5] = (t0 + t1 + t2 + t3 + t4) * 0.2f;
        }
    }
    __syncthreads();

    // wave0: per-q MLP, butterfly-sum, score write + fence-free atomic doc head
    if (wid == 0) {
        float val = 0.f;
        if (lane < 30) {
            float lo = ws[OFF_LQ2B];
            for (int j = 0; j < 8; ++j) {
                float h = ws[OFF_LQ1B + j];
                for (int f = 0; f < 6; ++f) h += FE[lane][f] * ws[OFF_LQ1W + j*6 + f];
                h = h >= 0.f ? h : SLOPE * h;
                lo += h * ws[OFF_LQ2W + j];
            }
            val = lo * ws[OFF_QW + lane];
        }
        for (int d = 32; d >= 1; d >>= 1) val += __shfl_xor(val, d);
        if (lane == 0) {
            float emit = val * (1.f / 30.f);
            float z = ws[OFF_SOB];
            z += ldx(gaf_in, (long)n*3 + 0, bf) * ws[OFF_SOW + 0];
            z += ldx(gaf_in, (long)n*3 + 1, bf) * ws[OFF_SOW + 1];
            z += ldx(gaf_in, (long)n*3 + 2, bf) * ws[OFF_SOW + 2];
            z += emit * ws[OFF_SOW + 3];
            float sc = 1.f / (1.f + expf(-z));
            if (bf) ((__hip_bfloat16*)out)[1 + n] = __float2bfloat16(sc);
            else    ((float*)out)[1 + n] = sc;

            // doc head via device-coherent atomics only (no threadfence / L2 flush):
            // sc in (0,1) => f32 bits are order-preserving positive ints.
            uint* ctl = (uint*)ws;
            atomicMax(ctl + 2, __float_as_uint(sc));
            // ensure the max RMW completed at the coherence point before counting
            __asm__ volatile("s_waitcnt vmcnt(0)" ::: "memory");
            uint old = atomicAdd(ctl + 1, 1u);
            if (old == 3999u) {
                uint mb = atomicOr(ctl + 2, 0u);   // coherent read-back via RMW
                float mx = __uint_as_float(mb);
                float f = ws[OFF_FLB] + mx * ws[OFF_FLW + 0];
                for (int i = 0; i < 4; ++i) f += ldx(docgaf_in, i, bf) * ws[OFF_FLW + 1 + i];
                if (bf) ((__hip_bfloat16*)out)[0] = __float2bfloat16(f);
                else    ((float*)out)[0] = f;
            }
        }
    }
}

extern "C" void kernel_launch(void* const* d_in, const int* in_sizes, int n_in,
                              void* d_out, int out_size, void* d_ws, size_t ws_size,
                              hipStream_t stream) {
    float* ws = (float*)d_ws;
    k_prep<<<3, 256, 0, stream>>>(d_in[0], d_in[2], d_in[3], d_in[5], d_in[6], d_in[7], d_in[8],
                                  d_in[9], d_in[10], d_in[11], d_in[12], d_in[13], d_in[14],
                                  d_in[15], d_in[16], d_in[17], d_in[18], ws);
    k_main<<<4000, 256, 0, stream>>>(d_in[0], d_in[1], d_in[4], d_out, ws);
}

// Round 5
// 207.317 us; speedup vs baseline: 2.1711x; 1.2394x over previous
//
#include <hip/hip_runtime.h>
#include <hip/hip_bf16.h>

#define SLOPE 0.1f

// ---- ws int-index layout: [0]=bf flag ----
// ---- ws float-index layout ----
#define OFF_QW    1816    // 30   q_weights (softmax)
#define OFF_QNI   1846    // 30   1/||question_embeds[q]||
#define OFF_QNS   1876    // 30   1/||q_conv[q]||
#define OFF_B1    4606    // 30
#define OFF_B2    7336    // 30
#define OFF_LQ1W  7366    // 48
#define OFF_LQ1B  7414    // 8
#define OFF_LQ2W  7422    // 8
#define OFF_LQ2B  7430    // 1
#define OFF_SOW   7431    // 4
#define OFF_SOB   7435    // 1
#define OFF_FLW   7436    // 5
#define OFF_FLB   7441    // 1
// ---- bf16 (u16-index) region, starts at byte 32768 ----
#define U16_QEA   16384   // 32 rows x 32  (A-operand QE, zeros at d>=30, q>=30)
#define U16_QCA   17408   // 32 rows x 32  (A-operand QC)
#define U16_WB1   18432   // 32 rows x 96  (B-operand conv1 W[o][kk], kk=k*30+i)
#define U16_WB2   21504   // 32 rows x 96

typedef __attribute__((ext_vector_type(8))) __bf16 bf16x8;
typedef __attribute__((ext_vector_type(4))) float f32x4;

union Frag { uint4 u4; uint u[4]; bf16x8 v; };

__device__ __forceinline__ float bf2f(ushort h) {
    union { uint u; float f; } c; c.u = ((uint)h) << 16; return c.f;
}
__device__ __forceinline__ ushort f2bf(float f) {   // RNE, finite inputs
    union { float f; uint u; } c; c.f = f;
    uint u = c.u;
    return (ushort)((u + 0x7FFFu + ((u >> 16) & 1u)) >> 16);
}
__device__ __forceinline__ float ldx(const void* p, long i, int bf) {
    if (bf) return bf2f(((const ushort*)p)[i]);
    return ((const float*)p)[i];
}
__device__ __forceinline__ void top5_insert(float v, float& t0, float& t1,
                                            float& t2, float& t3, float& t4) {
    bool b0 = v > t0, b1 = v > t1, b2 = v > t2, b3 = v > t3, b4 = v > t4;
    float n0 = b0 ? v  : t0;
    float n1 = b0 ? t0 : (b1 ? v : t1);
    float n2 = b1 ? t1 : (b2 ? v : t2);
    float n3 = b2 ? t2 : (b3 ? v : t3);
    float n4 = b3 ? t3 : (b4 ? v : t4);
    t0 = n0; t1 = n1; t2 = n2; t3 = n3; t4 = n4;
}
// dtype detection: f32 mantissa words carry wild bf16-exponent fields
__device__ __forceinline__ int detect_bf(const void* doc_in, int tid, int* scnt) {
    if (tid == 0) *scnt = 0;
    __syncthreads();
    const ushort* p = (const ushort*)doc_in;
    int local = 0;
    for (int i = tid; i < 4096; i += 256) {
        unsigned e = (p[i] >> 7) & 0xFFu;
        if (e != 0u && (e < 100u || e > 134u)) local++;
    }
    atomicAdd(scnt, local);
    __syncthreads();
    return (*scnt > 200) ? 0 : 1;
}

// ---------------- kernel 1 (3 blocks): detect + question path + repack ----------------
__global__ __launch_bounds__(256) void k_prep(
        const void* doc_in,
        const void* qe_in, const void* qidf_in,
        const void* w1_in, const void* b1_in,
        const void* w2_in, const void* b2_in,
        const void* qwW_in, const void* qwb_in,
        const void* lq1W_in, const void* lq1b_in,
        const void* lq2W_in, const void* lq2b_in,
        const void* soW_in, const void* sob_in,
        const void* flW_in, const void* flb_in,
        float* ws) {
    const int tid = threadIdx.x;
    const int blk = blockIdx.x;
    __shared__ float QE[900], T1[900], QC[900], W[2700], IDF[32], LG[32];
    __shared__ int scnt;

    const int bf = detect_bf(doc_in, tid, &scnt);
    ushort* wsu = (ushort*)ws;

    if (blk == 1) {
        if (tid == 0) { ((int*)ws)[0] = bf; }
        if (tid < 30) ws[OFF_B1 + tid] = ldx(b1_in, tid, bf);
        if (tid < 48) ws[OFF_LQ1W + tid] = ldx(lq1W_in, tid, bf);
        if (tid < 8)  { ws[OFF_LQ1B + tid] = ldx(lq1b_in, tid, bf);
                        ws[OFF_LQ2W + tid] = ldx(lq2W_in, tid, bf); }
        if (tid < 4)  ws[OFF_SOW + tid] = ldx(soW_in, tid, bf);
        if (tid < 5)  ws[OFF_FLW + tid] = ldx(flW_in, tid, bf);
        if (tid == 1) { ws[OFF_LQ2B] = ldx(lq2b_in, 0, bf);
                        ws[OFF_SOB]  = ldx(sob_in, 0, bf);
                        ws[OFF_FLB]  = ldx(flb_in, 0, bf); }
        for (int i = tid; i < 3072; i += 256) {
            int o = i / 96, kk = i % 96;
            float v1 = 0.f;
            if (o < 30 && kk < 90) {
                int ii = kk % 30, k = kk / 30;
                v1 = ldx(w1_in, (long)o*90 + ii*3 + k, bf);
            }
            wsu[U16_WB1 + i] = f2bf(v1);
        }
        return;
    }
    if (blk == 2) {
        if (tid < 30) ws[OFF_B2 + tid] = ldx(b2_in, tid, bf);
        for (int i = tid; i < 3072; i += 256) {
            int o = i / 96, kk = i % 96;
            float v2 = 0.f;
            if (o < 30 && kk < 90) {
                int ii = kk % 30, k = kk / 30;
                v2 = ldx(w2_in, (long)o*90 + ii*3 + k, bf);
            }
            wsu[U16_WB2 + i] = f2bf(v2);
        }
        return;
    }

    // ---- block 0: control word + question path ----
    if (tid == 0) { ((int*)ws)[0] = bf; }

    for (int i = tid; i < 900; i += 256) QE[i] = ldx(qe_in, i, bf);
    if (tid < 30) IDF[tid] = ldx(qidf_in, tid, bf);
    for (int i = tid; i < 2700; i += 256) W[i] = ldx(w1_in, i, bf);
    __syncthreads();

    for (int idx = tid; idx < 900; idx += 256) {
        int s = idx / 30, o = idx % 30;
        float acc = ldx(b1_in, o, bf);
        for (int k = 0; k < 3; ++k) {
            int t = s + k - 1;
            if (t < 0 || t >= 30) continue;
            for (int i = 0; i < 30; ++i) acc += QE[t*30 + i] * W[o*90 + i*3 + k];
        }
        acc = acc >= 0.f ? acc : SLOPE * acc;
        T1[idx] = acc + QE[idx];
    }
    __syncthreads();
    for (int i = tid; i < 2700; i += 256) W[i] = ldx(w2_in, i, bf);
    __syncthreads();
    for (int idx = tid; idx < 900; idx += 256) {
        int s = idx / 30, o = idx % 30;
        float acc = ldx(b2_in, o, bf);
        for (int k = 0; k < 3; ++k) {
            int t = s + k - 1;
            if (t < 0 || t >= 30) continue;
            for (int i = 0; i < 30; ++i) acc += T1[t*30 + i] * W[o*90 + i*3 + k];
        }
        acc = acc >= 0.f ? acc : SLOPE * acc;
        QC[idx] = acc + T1[idx];
    }
    __syncthreads();

    if (tid < 30) {
        float s1 = 0.f, s2 = 0.f;
        for (int d = 0; d < 30; ++d) {
            float a = QE[tid*30 + d]; s1 += a*a;
            float b = QC[tid*30 + d]; s2 += b*b;
        }
        ws[OFF_QNI + tid] = 1.0f / sqrtf(s1);
        ws[OFF_QNS + tid] = 1.0f / sqrtf(s2);
        float z = ldx(qwb_in, 0, bf);
        for (int d = 0; d < 30; ++d) z += QC[tid*30 + d] * ldx(qwW_in, d, bf);
        z += IDF[tid] * ldx(qwW_in, 30, bf);
        LG[tid] = z;
    }
    __syncthreads();
    if (tid == 0) {
        float m = -1e30f;
        for (int q = 0; q < 30; ++q) m = fmaxf(m, LG[q]);
        float sum = 0.f, e[30];
        for (int q = 0; q < 30; ++q) { e[q] = expf(LG[q] - m); sum += e[q]; }
        for (int q = 0; q < 30; ++q) ws[OFF_QW + q] = e[q] / sum;
    }
    for (int i = tid; i < 1024; i += 256) {
        int q = i >> 5, d = i & 31;
        float ve = (q < 30 && d < 30) ? QE[q*30 + d] : 0.f;
        float vc = (q < 30 && d < 30) ? QC[q*30 + d] : 0.f;
        wsu[U16_QEA + i] = f2bf(ve);
        wsu[U16_QCA + i] = f2bf(vc);
    }
}

// ---------------- kernel 2: per-sentence fused MFMA pipeline ----------------
// block = 128 (2 waves). wave w owns sim q-tile mt=w (register-resident pooling).
__global__ __launch_bounds__(128, 4) void k_main(const void* doc_in, const void* gaf_in,
                                                 void* out, float* ws) {
    const int n = blockIdx.x;
    const int tid = threadIdx.x;
    const int bf = ((const int*)ws)[0];
    const int lane = tid & 63;
    const int wid = tid >> 6;          // 0 or 1
    const int l15 = lane & 15;
    const int quad = lane >> 4;

    __shared__ uint XA32[1546];        // X flat bf16: 103 rows x 30 (rows 0,101,102 zero)
    __shared__ uint XB32[1546];        // conv1 output, same layout
    __shared__ float INVX[100];
    __shared__ float FE[30][6];
    __shared__ float IQI[30], IQS[30], BI1[30], BI2[30];

    ushort* XAu = (ushort*)XA32;
    const ushort* wsu = (const ushort*)ws;
    const uint4* qeA = (const uint4*)(wsu + U16_QEA);
    const uint4* qcA = (const uint4*)(wsu + U16_QCA);
    const uint4* wb1 = (const uint4*)(wsu + U16_WB1);
    const uint4* wb2 = (const uint4*)(wsu + U16_WB2);

    // ---- B0: zero pads, load sentence, cache small params in LDS ----
    for (int i = tid; i < 46; i += 128) {
        int j = (i < 15) ? i : (1500 + i);   // [0,15) and [1515,1546)
        XA32[j] = 0u; XB32[j] = 0u;
    }
    if (bf) {
        const uint* g = (const uint*)((const ushort*)doc_in + (size_t)n * 3000);
        for (int i = tid; i < 1500; i += 128) XA32[15 + i] = g[i];
    } else {
        const float* p = (const float*)doc_in + (size_t)n * 3000;
        for (int i = tid; i < 3000; i += 128) XAu[30 + i] = f2bf(p[i]);
    }
    if (tid < 30) {
        IQI[tid] = ws[OFF_QNI + tid];
        IQS[tid] = ws[OFF_QNS + tid];
        BI1[tid] = ws[OFF_B1 + tid];
        BI2[tid] = ws[OFF_B2 + tid];
    }
    __syncthreads();

    // ---- B1: inverse row norms of X ----
    if (tid < 100) {
        const uint* r = XA32 + (tid + 1) * 15;
        float s = 0.f;
        #pragma unroll
        for (int i = 0; i < 15; ++i) {
            uint u = r[i];
            float lo = __uint_as_float(u << 16);
            float hi = __uint_as_float(u & 0xFFFF0000u);
            s += lo * lo + hi * hi;
        }
        INVX[tid] = 1.f / sqrtf(s);
    }
    __syncthreads();

    // register-resident sim + pool for this wave's mt = wid
    auto sim_pool = [&](const uint4* qa, const float* invq, int fbase, bool do_oh) {
        f32x4 acc[7];
        Frag a;
        a.u4 = qa[(wid * 16 + l15) * 4 + quad];
        #pragma unroll
        for (int nt = 0; nt < 7; ++nt) {
            int s = nt * 16 + l15;
            Frag b;
            if (s < 100) {
                int base = (s + 1) * 15 + quad * 4;
                b.u[0] = XA32[base];     b.u[1] = XA32[base + 1];
                b.u[2] = XA32[base + 2]; b.u[3] = XA32[base + 3];
            } else { b.u[0] = b.u[1] = b.u[2] = b.u[3] = 0u; }
            f32x4 z = {0.f, 0.f, 0.f, 0.f};
            acc[nt] = __builtin_amdgcn_mfma_f32_16x16x32_bf16(a.v, b.v, z, 0, 0, 0);
        }
        float ix[7];
        #pragma unroll
        for (int nt = 0; nt < 7; ++nt) {
            int s = nt * 16 + l15;
            ix[nt] = (s < 100) ? INVX[s] : 0.f;
        }
        #pragma unroll
        for (int r = 0; r < 4; ++r) {
            int q = wid * 16 + quad * 4 + r;
            float iq = (q < 30) ? invq[q] : 0.f;
            float t0=-1e30f, t1=-1e30f, t2=-1e30f, t3=-1e30f, t4=-1e30f;
            int cnt = 0;
            #pragma unroll
            for (int nt = 0; nt < 7; ++nt) {
                int s = nt * 16 + l15;
                float v = (s < 100) ? acc[nt][r] * iq * ix[nt] : -1e30f;
                if (do_oh) cnt += (v > 0.999f) ? 1 : 0;
                top5_insert(v, t0, t1, t2, t3, t4);
            }
            #pragma unroll
            for (int d = 1; d < 16; d <<= 1) {       // butterfly within the 16-lane quad
                float p0 = __shfl_xor(t0, d), p1 = __shfl_xor(t1, d), p2 = __shfl_xor(t2, d);
                float p3 = __shfl_xor(t3, d), p4 = __shfl_xor(t4, d);
                if (do_oh) cnt += __shfl_xor(cnt, d);
                top5_insert(p0, t0, t1, t2, t3, t4);
                top5_insert(p1, t0, t1, t2, t3, t4);
                top5_insert(p2, t0, t1, t2, t3, t4);
                top5_insert(p3, t0, t1, t2, t3, t4);
                top5_insert(p4, t0, t1, t2, t3, t4);
            }
            if (l15 == 0 && q < 30) {
                if (do_oh) {
                    FE[q][0] = cnt > 0 ? 1.f : 0.f;
                    FE[q][1] = (float)(cnt > 5 ? 5 : cnt) * 0.2f;
                }
                FE[q][fbase]     = t0;
                FE[q][fbase + 1] = (t0 + t1 + t2 + t3 + t4) * 0.2f;
            }
        }
    };

    // conv for one mt; A-fragments shared across nt tiles [nt0, nt1]
    auto conv_mt = [&](const uint* src32, uint* dst32, const uint4* wb,
                       const float* bias, int mt, int nt0, int nt1) {
        const ushort* srcU = (const ushort*)src32;
        ushort* dstU = (ushort*)dst32;
        int sa = mt * 16 + l15;
        Frag a[3];
        #pragma unroll
        for (int k = 0; k < 3; ++k) {
            if (sa < 100) {
                int base = sa * 15 + k * 16 + quad * 4;
                a[k].u[0] = src32[base];     a[k].u[1] = src32[base + 1];
                a[k].u[2] = src32[base + 2]; a[k].u[3] = src32[base + 3];
            } else { a[k].u[0] = a[k].u[1] = a[k].u[2] = a[k].u[3] = 0u; }
        }
        for (int nt = nt0; nt <= nt1; ++nt) {
            f32x4 acc = {0.f, 0.f, 0.f, 0.f};
            #pragma unroll
            for (int k = 0; k < 3; ++k) {
                Frag b;
                b.u4 = wb[(nt * 16 + l15) * 12 + k * 4 + quad];
                acc = __builtin_amdgcn_mfma_f32_16x16x32_bf16(a[k].v, b.v, acc, 0, 0, 0);
            }
            int o = nt * 16 + l15;
            if (o < 30) {
                float bo = bias[o];
                #pragma unroll
                for (int r = 0; r < 4; ++r) {
                    int s = mt * 16 + quad * 4 + r;
                    if (s < 100) {
                        float v = acc[r] + bo;
                        v = v >= 0.f ? v : SLOPE * v;
                        v += bf2f(srcU[(s + 1) * 30 + o]);
                        dstU[(s + 1) * 30 + o] = f2bf(v);
                    }
                }
            }
        }
    };

    // ---- B2: sim_insens + pool (registers) then conv1 XA->XB ----
    sim_pool(qeA, IQI, 2, true);
    conv_mt(XA32, XB32, wb1, BI1, wid,     0, 1);
    conv_mt(XA32, XB32, wb1, BI1, wid + 2, 0, 1);
    conv_mt(XA32, XB32, wb1, BI1, wid + 4, 0, 1);
    conv_mt(XA32, XB32, wb1, BI1, 6,       wid, wid);
    __syncthreads();

    // ---- B3: conv2 XB->XA ----
    conv_mt(XB32, XA32, wb2, BI2, wid,     0, 1);
    conv_mt(XB32, XA32, wb2, BI2, wid + 2, 0, 1);
    conv_mt(XB32, XA32, wb2, BI2, wid + 4, 0, 1);
    conv_mt(XB32, XA32, wb2, BI2, 6,       wid, wid);
    __syncthreads();

    // ---- B4: inverse row norms of conv_res ----
    if (tid < 100) {
        const uint* r = XA32 + (tid + 1) * 15;
        float s = 0.f;
        #pragma unroll
        for (int i = 0; i < 15; ++i) {
            uint u = r[i];
            float lo = __uint_as_float(u << 16);
            float hi = __uint_as_float(u & 0xFFFF0000u);
            s += lo * lo + hi * hi;
        }
        INVX[tid] = 1.f / sqrtf(s);
    }
    __syncthreads();

    // ---- B5: sim_sens + pool (registers) ----
    sim_pool(qcA, IQS, 4, false);
    __syncthreads();

    // ---- B6: wave0: per-q MLP, butterfly-sum, score write ----
    if (wid == 0) {
        float val = 0.f;
        if (lane < 30) {
            float lo = ws[OFF_LQ2B];
            #pragma unroll
            for (int j = 0; j < 8; ++j) {
                float h = ws[OFF_LQ1B + j];
                #pragma unroll
                for (int f = 0; f < 6; ++f) h += FE[lane][f] * ws[OFF_LQ1W + j*6 + f];
                h = h >= 0.f ? h : SLOPE * h;
                lo += h * ws[OFF_LQ2W + j];
            }
            val = lo * ws[OFF_QW + lane];
        }
        for (int d = 32; d >= 1; d >>= 1) val += __shfl_xor(val, d);
        if (lane == 0) {
            float emit = val * (1.f / 30.f);
            float z = ws[OFF_SOB];
            z += ldx(gaf_in, (long)n*3 + 0, bf) * ws[OFF_SOW + 0];
            z += ldx(gaf_in, (long)n*3 + 1, bf) * ws[OFF_SOW + 1];
            z += ldx(gaf_in, (long)n*3 + 2, bf) * ws[OFF_SOW + 2];
            z += emit * ws[OFF_SOW + 3];
            float sc = 1.f / (1.f + expf(-z));
            if (bf) ((__hip_bfloat16*)out)[1 + n] = __float2bfloat16(sc);
            else    ((float*)out)[1 + n] = sc;
        }
    }
}

// ---------------- kernel 3: doc-level head ----------------
__global__ __launch_bounds__(256) void k_final(const void* docgaf_in, void* out, const float* ws) {
    const int tid = threadIdx.x;
    const int bf = ((const int*)ws)[0];
    __shared__ float red[256];
    float m = -1e30f;
    for (int i = tid; i < 4000; i += 256) {
        float v = bf ? __bfloat162float(((const __hip_bfloat16*)out)[1 + i])
                     : ((const float*)out)[1 + i];
        m = fmaxf(m, v);
    }
    red[tid] = m;
    __syncthreads();
    for (int off = 128; off > 0; off >>= 1) {
        if (tid < off) red[tid] = fmaxf(red[tid], red[tid + off]);
        __syncthreads();
    }
    if (tid == 0) {
        float f = ws[OFF_FLB] + red[0] * ws[OFF_FLW + 0];
        for (int i = 0; i < 4; ++i) f += ldx(docgaf_in, i, bf) * ws[OFF_FLW + 1 + i];
        if (bf) ((__hip_bfloat16*)out)[0] = __float2bfloat16(f);
        else    ((float*)out)[0] = f;
    }
}

extern "C" void kernel_launch(void* const* d_in, const int* in_sizes, int n_in,
                              void* d_out, int out_size, void* d_ws, size_t ws_size,
                              hipStream_t stream) {
    float* ws = (float*)d_ws;
    k_prep<<<3, 256, 0, stream>>>(d_in[0], d_in[2], d_in[3], d_in[5], d_in[6], d_in[7], d_in[8],
                                  d_in[9], d_in[10], d_in[11], d_in[12], d_in[13], d_in[14],
                                  d_in[15], d_in[16], d_in[17], d_in[18], ws);
    k_main<<<4000, 128, 0, stream>>>(d_in[0], d_in[1], d_out, ws);
    k_final<<<1, 256, 0, stream>>>(d_in[4], d_out, ws);
}

// Round 6
// 189.247 us; speedup vs baseline: 2.3784x; 1.0955x over previous
//
#include <hip/hip_runtime.h>
#include <hip/hip_bf16.h>

#define SLOPE 0.1f

// ---- ws int-index layout: [0]=bf flag ----
// ---- ws float-index layout ----
#define OFF_QW    1816    // 30   q_weights (softmax)
#define OFF_QNI   1846    // 30   1/||question_embeds[q]||
#define OFF_QNS   1876    // 30   1/||q_conv[q]||
#define OFF_B1    4606    // 30
#define OFF_B2    7336    // 30
#define OFF_LQ1W  7366    // 48
#define OFF_LQ1B  7414    // 8
#define OFF_LQ2W  7422    // 8
#define OFF_LQ2B  7430    // 1
#define OFF_SOW   7431    // 4
#define OFF_SOB   7435    // 1
#define OFF_FLW   7436    // 5
#define OFF_FLB   7441    // 1
// ---- bf16 (u16-index) region, starts at byte 32768 ----
#define U16_QEA   16384   // 32 rows x 32  (A-operand QE, zeros at d>=30, q>=30)
#define U16_QCA   17408   // 32 rows x 32  (A-operand QC)
#define U16_WB1   18432   // 32 rows x 96  (B-operand conv1 W[o][kk], kk=k*30+i)
#define U16_WB2   21504   // 32 rows x 96

typedef __attribute__((ext_vector_type(8))) __bf16 bf16x8;
typedef __attribute__((ext_vector_type(4))) float f32x4;

union Frag { uint4 u4; uint u[4]; bf16x8 v; };

__device__ __forceinline__ float bf2f(ushort h) {
    union { uint u; float f; } c; c.u = ((uint)h) << 16; return c.f;
}
__device__ __forceinline__ ushort f2bf(float f) {   // RNE, finite inputs
    union { float f; uint u; } c; c.f = f;
    uint u = c.u;
    return (ushort)((u + 0x7FFFu + ((u >> 16) & 1u)) >> 16);
}
__device__ __forceinline__ float ldx(const void* p, long i, int bf) {
    if (bf) return bf2f(((const ushort*)p)[i]);
    return ((const float*)p)[i];
}
#define CE(x, y) { float _hi = fmaxf(x, y), _lo = fminf(x, y); x = _hi; y = _lo; }

// dtype detection: f32 mantissa words carry wild bf16-exponent fields
__device__ __forceinline__ int detect_bf(const void* doc_in, int tid, int* scnt) {
    if (tid == 0) *scnt = 0;
    __syncthreads();
    const ushort* p = (const ushort*)doc_in;
    int local = 0;
    for (int i = tid; i < 4096; i += 256) {
        unsigned e = (p[i] >> 7) & 0xFFu;
        if (e != 0u && (e < 100u || e > 134u)) local++;
    }
    atomicAdd(scnt, local);
    __syncthreads();
    return (*scnt > 200) ? 0 : 1;
}

// ---------------- kernel 1 (3 blocks): detect + question path + repack ----------------
__global__ __launch_bounds__(256) void k_prep(
        const void* doc_in,
        const void* qe_in, const void* qidf_in,
        const void* w1_in, const void* b1_in,
        const void* w2_in, const void* b2_in,
        const void* qwW_in, const void* qwb_in,
        const void* lq1W_in, const void* lq1b_in,
        const void* lq2W_in, const void* lq2b_in,
        const void* soW_in, const void* sob_in,
        const void* flW_in, const void* flb_in,
        float* ws) {
    const int tid = threadIdx.x;
    const int blk = blockIdx.x;
    __shared__ float QE[900], T1[900], QC[900], W[2700], IDF[32], LG[32];
    __shared__ int scnt;

    const int bf = detect_bf(doc_in, tid, &scnt);
    ushort* wsu = (ushort*)ws;

    if (blk == 1) {
        if (tid == 0) { ((int*)ws)[0] = bf; }
        if (tid < 30) ws[OFF_B1 + tid] = ldx(b1_in, tid, bf);
        if (tid < 48) ws[OFF_LQ1W + tid] = ldx(lq1W_in, tid, bf);
        if (tid < 8)  { ws[OFF_LQ1B + tid] = ldx(lq1b_in, tid, bf);
                        ws[OFF_LQ2W + tid] = ldx(lq2W_in, tid, bf); }
        if (tid < 4)  ws[OFF_SOW + tid] = ldx(soW_in, tid, bf);
        if (tid < 5)  ws[OFF_FLW + tid] = ldx(flW_in, tid, bf);
        if (tid == 1) { ws[OFF_LQ2B] = ldx(lq2b_in, 0, bf);
                        ws[OFF_SOB]  = ldx(sob_in, 0, bf);
                        ws[OFF_FLB]  = ldx(flb_in, 0, bf); }
        for (int i = tid; i < 3072; i += 256) {
            int o = i / 96, kk = i % 96;
            float v1 = 0.f;
            if (o < 30 && kk < 90) {
                int ii = kk % 30, k = kk / 30;
                v1 = ldx(w1_in, (long)o*90 + ii*3 + k, bf);
            }
            wsu[U16_WB1 + i] = f2bf(v1);
        }
        return;
    }
    if (blk == 2) {
        if (tid < 30) ws[OFF_B2 + tid] = ldx(b2_in, tid, bf);
        for (int i = tid; i < 3072; i += 256) {
            int o = i / 96, kk = i % 96;
            float v2 = 0.f;
            if (o < 30 && kk < 90) {
                int ii = kk % 30, k = kk / 30;
                v2 = ldx(w2_in, (long)o*90 + ii*3 + k, bf);
            }
            wsu[U16_WB2 + i] = f2bf(v2);
        }
        return;
    }

    // ---- block 0: control word + question path ----
    if (tid == 0) { ((int*)ws)[0] = bf; }

    for (int i = tid; i < 900; i += 256) QE[i] = ldx(qe_in, i, bf);
    if (tid < 30) IDF[tid] = ldx(qidf_in, tid, bf);
    for (int i = tid; i < 2700; i += 256) W[i] = ldx(w1_in, i, bf);
    __syncthreads();

    for (int idx = tid; idx < 900; idx += 256) {
        int s = idx / 30, o = idx % 30;
        float acc = ldx(b1_in, o, bf);
        for (int k = 0; k < 3; ++k) {
            int t = s + k - 1;
            if (t < 0 || t >= 30) continue;
            for (int i = 0; i < 30; ++i) acc += QE[t*30 + i] * W[o*90 + i*3 + k];
        }
        acc = acc >= 0.f ? acc : SLOPE * acc;
        T1[idx] = acc + QE[idx];
    }
    __syncthreads();
    for (int i = tid; i < 2700; i += 256) W[i] = ldx(w2_in, i, bf);
    __syncthreads();
    for (int idx = tid; idx < 900; idx += 256) {
        int s = idx / 30, o = idx % 30;
        float acc = ldx(b2_in, o, bf);
        for (int k = 0; k < 3; ++k) {
            int t = s + k - 1;
            if (t < 0 || t >= 30) continue;
            for (int i = 0; i < 30; ++i) acc += T1[t*30 + i] * W[o*90 + i*3 + k];
        }
        acc = acc >= 0.f ? acc : SLOPE * acc;
        QC[idx] = acc + T1[idx];
    }
    __syncthreads();

    if (tid < 30) {
        float s1 = 0.f, s2 = 0.f;
        for (int d = 0; d < 30; ++d) {
            float a = QE[tid*30 + d]; s1 += a*a;
            float b = QC[tid*30 + d]; s2 += b*b;
        }
        ws[OFF_QNI + tid] = 1.0f / sqrtf(s1);
        ws[OFF_QNS + tid] = 1.0f / sqrtf(s2);
        float z = ldx(qwb_in, 0, bf);
        for (int d = 0; d < 30; ++d) z += QC[tid*30 + d] * ldx(qwW_in, d, bf);
        z += IDF[tid] * ldx(qwW_in, 30, bf);
        LG[tid] = z;
    }
    __syncthreads();
    if (tid == 0) {
        float m = -1e30f;
        for (int q = 0; q < 30; ++q) m = fmaxf(m, LG[q]);
        float sum = 0.f, e[30];
        for (int q = 0; q < 30; ++q) { e[q] = expf(LG[q] - m); sum += e[q]; }
        for (int q = 0; q < 30; ++q) ws[OFF_QW + q] = e[q] / sum;
    }
    for (int i = tid; i < 1024; i += 256) {
        int q = i >> 5, d = i & 31;
        float ve = (q < 30 && d < 30) ? QE[q*30 + d] : 0.f;
        float vc = (q < 30 && d < 30) ? QC[q*30 + d] : 0.f;
        wsu[U16_QEA + i] = f2bf(ve);
        wsu[U16_QCA + i] = f2bf(vc);
    }
}

// ---------------- kernel 2: per-sentence fused MFMA pipeline ----------------
// block = 128 (2 waves). wave w owns sim q-tile mt=w (register-resident pooling
// with min3/max3 merge networks instead of serial insertion).
__global__ __launch_bounds__(128, 4) void k_main(const void* doc_in, const void* gaf_in,
                                                 void* out, float* ws) {
    const int n = blockIdx.x;
    const int tid = threadIdx.x;
    const int bf = ((const int*)ws)[0];
    const int lane = tid & 63;
    const int wid = tid >> 6;          // 0 or 1
    const int l15 = lane & 15;
    const int quad = lane >> 4;

    __shared__ uint XA32[1546];        // X flat bf16: 103 rows x 30 (rows 0,101,102 zero)
    __shared__ uint XB32[1546];        // conv1 output, same layout
    __shared__ float INVX[100];
    __shared__ float FE[30][6];
    __shared__ float IQI[30], IQS[30], BI1[30], BI2[30];

    ushort* XAu = (ushort*)XA32;
    const ushort* wsu = (const ushort*)ws;
    const uint4* qeA = (const uint4*)(wsu + U16_QEA);
    const uint4* qcA = (const uint4*)(wsu + U16_QCA);
    const uint4* wb1 = (const uint4*)(wsu + U16_WB1);
    const uint4* wb2 = (const uint4*)(wsu + U16_WB2);

    // prefetch gaf scalars (consumed at the very end by wave0 lane0)
    float ga0 = ldx(gaf_in, (long)n*3 + 0, bf);
    float ga1 = ldx(gaf_in, (long)n*3 + 1, bf);
    float ga2 = ldx(gaf_in, (long)n*3 + 2, bf);

    // ---- B0: zero pads, load sentence, cache small params in LDS ----
    for (int i = tid; i < 46; i += 128) {
        int j = (i < 15) ? i : (1500 + i);   // [0,15) and [1515,1546)
        XA32[j] = 0u; XB32[j] = 0u;
    }
    if (bf) {
        const uint* g = (const uint*)((const ushort*)doc_in + (size_t)n * 3000);
        for (int i = tid; i < 1500; i += 128) XA32[15 + i] = g[i];
    } else {
        const float* p = (const float*)doc_in + (size_t)n * 3000;
        for (int i = tid; i < 3000; i += 128) XAu[30 + i] = f2bf(p[i]);
    }
    if (tid < 30) {
        IQI[tid] = ws[OFF_QNI + tid];
        IQS[tid] = ws[OFF_QNS + tid];
        BI1[tid] = ws[OFF_B1 + tid];
        BI2[tid] = ws[OFF_B2 + tid];
    }
    __syncthreads();

    // ---- B1: inverse row norms of X ----
    if (tid < 100) {
        const uint* r = XA32 + (tid + 1) * 15;
        float s = 0.f;
        #pragma unroll
        for (int i = 0; i < 15; ++i) {
            uint u = r[i];
            float lo = __uint_as_float(u << 16);
            float hi = __uint_as_float(u & 0xFFFF0000u);
            s += lo * lo + hi * hi;
        }
        INVX[tid] = 1.f / sqrtf(s);
    }
    __syncthreads();

    // register-resident sim + pool for this wave's mt = wid
    auto sim_pool = [&](const uint4* qa, const float* invq, int fbase, bool do_oh) {
        f32x4 acc[7];
        Frag a;
        a.u4 = qa[(wid * 16 + l15) * 4 + quad];
        #pragma unroll
        for (int nt = 0; nt < 7; ++nt) {
            int s = nt * 16 + l15;
            Frag b;
            if (s < 100) {
                int base = (s + 1) * 15 + quad * 4;
                b.u[0] = XA32[base];     b.u[1] = XA32[base + 1];
                b.u[2] = XA32[base + 2]; b.u[3] = XA32[base + 3];
            } else { b.u[0] = b.u[1] = b.u[2] = b.u[3] = 0u; }
            f32x4 z = {0.f, 0.f, 0.f, 0.f};
            acc[nt] = __builtin_amdgcn_mfma_f32_16x16x32_bf16(a.v, b.v, z, 0, 0, 0);
        }
        float ix[7];
        #pragma unroll
        for (int nt = 0; nt < 7; ++nt) {
            int s = nt * 16 + l15;
            ix[nt] = (s < 100) ? INVX[s] : 0.f;
        }
        #pragma unroll
        for (int r = 0; r < 4; ++r) {
            int q = wid * 16 + quad * 4 + r;
            float iq = (q < 30) ? invq[q] : 0.f;
            float v[7];
            int cnt = 0;
            #pragma unroll
            for (int nt = 0; nt < 7; ++nt) {
                int s = nt * 16 + l15;
                v[nt] = (s < 100) ? acc[nt][r] * iq * ix[nt] : -1e30f;
                if (do_oh) cnt += (v[nt] > 0.999f) ? 1 : 0;
            }
            // top5-of-7: sort4(v0..v3) + sort3(v4..v6) + 4x3 merge network
            CE(v[0], v[1]); CE(v[2], v[3]); CE(v[0], v[2]); CE(v[1], v[3]); CE(v[1], v[2]);
            CE(v[4], v[5]); CE(v[5], v[6]); CE(v[4], v[5]);
            float t0 = fmaxf(v[0], v[4]);
            float t1 = fmaxf(fmaxf(fminf(v[0], v[4]), v[1]), v[5]);
            float t2 = fmaxf(fmaxf(fmaxf(fminf(v[0], v[5]), fminf(v[1], v[4])), v[2]), v[6]);
            float t3 = fmaxf(fmaxf(fmaxf(fminf(v[0], v[6]), fminf(v[1], v[5])), fminf(v[2], v[4])), v[3]);
            float t4 = fmaxf(fmaxf(fminf(v[1], v[6]), fminf(v[2], v[5])), fminf(v[3], v[4]));
            // butterfly across 16 lanes; 5+5 sorted-merge network per step
            #pragma unroll
            for (int d = 1; d < 16; d <<= 1) {
                float p0 = __shfl_xor(t0, d), p1 = __shfl_xor(t1, d), p2 = __shfl_xor(t2, d);
                float p3 = __shfl_xor(t3, d), p4 = __shfl_xor(t4, d);
                if (do_oh) cnt += __shfl_xor(cnt, d);
                float m0 = fmaxf(t0, p0);
                float m1 = fmaxf(fmaxf(fminf(t0, p0), t1), p1);
                float m2 = fmaxf(fmaxf(fmaxf(fminf(t0, p1), fminf(t1, p0)), t2), p2);
                float m3 = fmaxf(fmaxf(fmaxf(fminf(t0, p2), fminf(t1, p1)), fminf(t2, p0)),
                                 fmaxf(t3, p3));
                float m4 = fmaxf(fmaxf(fmaxf(fminf(t0, p3), fminf(t1, p2)), fminf(t2, p1)),
                                 fmaxf(fminf(t3, p0), fmaxf(t4, p4)));
                t0 = m0; t1 = m1; t2 = m2; t3 = m3; t4 = m4;
            }
            if (l15 == 0 && q < 30) {
                if (do_oh) {
                    FE[q][0] = cnt > 0 ? 1.f : 0.f;
                    FE[q][1] = (float)(cnt > 5 ? 5 : cnt) * 0.2f;
                }
                FE[q][fbase]     = t0;
                FE[q][fbase + 1] = (t0 + t1 + t2 + t3 + t4) * 0.2f;
            }
        }
    };

    // conv for one mt; A-fragments shared across nt tiles [nt0, nt1]
    auto conv_mt = [&](const uint* src32, uint* dst32, const uint4* wb,
                       const float* bias, int mt, int nt0, int nt1) {
        const ushort* srcU = (const ushort*)src32;
        ushort* dstU = (ushort*)dst32;
        int sa = mt * 16 + l15;
        Frag a[3];
        #pragma unroll
        for (int k = 0; k < 3; ++k) {
            if (sa < 100) {
                int base = sa * 15 + k * 16 + quad * 4;
                a[k].u[0] = src32[base];     a[k].u[1] = src32[base + 1];
                a[k].u[2] = src32[base + 2]; a[k].u[3] = src32[base + 3];
            } else { a[k].u[0] = a[k].u[1] = a[k].u[2] = a[k].u[3] = 0u; }
        }
        for (int nt = nt0; nt <= nt1; ++nt) {
            f32x4 acc = {0.f, 0.f, 0.f, 0.f};
            #pragma unroll
            for (int k = 0; k < 3; ++k) {
                Frag b;
                b.u4 = wb[(nt * 16 + l15) * 12 + k * 4 + quad];
                acc = __builtin_amdgcn_mfma_f32_16x16x32_bf16(a[k].v, b.v, acc, 0, 0, 0);
            }
            int o = nt * 16 + l15;
            if (o < 30) {
                float bo = bias[o];
                #pragma unroll
                for (int r = 0; r < 4; ++r) {
                    int s = mt * 16 + quad * 4 + r;
                    if (s < 100) {
                        float v = acc[r] + bo;
                        v = v >= 0.f ? v : SLOPE * v;
                        v += bf2f(srcU[(s + 1) * 30 + o]);
                        dstU[(s + 1) * 30 + o] = f2bf(v);
                    }
                }
            }
        }
    };

    // ---- B2: sim_insens + pool (registers) then conv1 XA->XB ----
    sim_pool(qeA, IQI, 2, true);
    conv_mt(XA32, XB32, wb1, BI1, wid,     0, 1);
    conv_mt(XA32, XB32, wb1, BI1, wid + 2, 0, 1);
    conv_mt(XA32, XB32, wb1, BI1, wid + 4, 0, 1);
    conv_mt(XA32, XB32, wb1, BI1, 6,       wid, wid);
    __syncthreads();

    // ---- B3: conv2 XB->XA ----
    conv_mt(XB32, XA32, wb2, BI2, wid,     0, 1);
    conv_mt(XB32, XA32, wb2, BI2, wid + 2, 0, 1);
    conv_mt(XB32, XA32, wb2, BI2, wid + 4, 0, 1);
    conv_mt(XB32, XA32, wb2, BI2, 6,       wid, wid);
    __syncthreads();

    // ---- B4: inverse row norms of conv_res ----
    if (tid < 100) {
        const uint* r = XA32 + (tid + 1) * 15;
        float s = 0.f;
        #pragma unroll
        for (int i = 0; i < 15; ++i) {
            uint u = r[i];
            float lo = __uint_as_float(u << 16);
            float hi = __uint_as_float(u & 0xFFFF0000u);
            s += lo * lo + hi * hi;
        }
        INVX[tid] = 1.f / sqrtf(s);
    }
    __syncthreads();

    // ---- B5: sim_sens + pool (registers) ----
    sim_pool(qcA, IQS, 4, false);
    __syncthreads();

    // ---- B6: wave0: per-q MLP, butterfly-sum, score write ----
    if (wid == 0) {
        float val = 0.f;
        if (lane < 30) {
            float lo = ws[OFF_LQ2B];
            #pragma unroll
            for (int j = 0; j < 8; ++j) {
                float h = ws[OFF_LQ1B + j];
                #pragma unroll
                for (int f = 0; f < 6; ++f) h += FE[lane][f] * ws[OFF_LQ1W + j*6 + f];
                h = h >= 0.f ? h : SLOPE * h;
                lo += h * ws[OFF_LQ2W + j];
            }
            val = lo * ws[OFF_QW + lane];
        }
        for (int d = 32; d >= 1; d >>= 1) val += __shfl_xor(val, d);
        if (lane == 0) {
            float emit = val * (1.f / 30.f);
            float z = ws[OFF_SOB];
            z += ga0 * ws[OFF_SOW + 0];
            z += ga1 * ws[OFF_SOW + 1];
            z += ga2 * ws[OFF_SOW + 2];
            z += emit * ws[OFF_SOW + 3];
            float sc = 1.f / (1.f + expf(-z));
            if (bf) ((__hip_bfloat16*)out)[1 + n] = __float2bfloat16(sc);
            else    ((float*)out)[1 + n] = sc;
        }
    }
}

// ---------------- kernel 3: doc-level head ----------------
__global__ __launch_bounds__(256) void k_final(const void* docgaf_in, void* out, const float* ws) {
    const int tid = threadIdx.x;
    const int bf = ((const int*)ws)[0];
    __shared__ float red[256];
    float m = -1e30f;
    for (int i = tid; i < 4000; i += 256) {
        float v = bf ? __bfloat162float(((const __hip_bfloat16*)out)[1 + i])
                     : ((const float*)out)[1 + i];
        m = fmaxf(m, v);
    }
    red[tid] = m;
    __syncthreads();
    for (int off = 128; off > 0; off >>= 1) {
        if (tid < off) red[tid] = fmaxf(red[tid], red[tid + off]);
        __syncthreads();
    }
    if (tid == 0) {
        float f = ws[OFF_FLB] + red[0] * ws[OFF_FLW + 0];
        for (int i = 0; i < 4; ++i) f += ldx(docgaf_in, i, bf) * ws[OFF_FLW + 1 + i];
        if (bf) ((__hip_bfloat16*)out)[0] = __float2bfloat16(f);
        else    ((float*)out)[0] = f;
    }
}

extern "C" void kernel_launch(void* const* d_in, const int* in_sizes, int n_in,
                              void* d_out, int out_size, void* d_ws, size_t ws_size,
                              hipStream_t stream) {
    float* ws = (float*)d_ws;
    k_prep<<<3, 256, 0, stream>>>(d_in[0], d_in[2], d_in[3], d_in[5], d_in[6], d_in[7], d_in[8],
                                  d_in[9], d_in[10], d_in[11], d_in[12], d_in[13], d_in[14],
                                  d_in[15], d_in[16], d_in[17], d_in[18], ws);
    k_main<<<4000, 128, 0, stream>>>(d_in[0], d_in[1], d_out, ws);
    k_final<<<1, 256, 0, stream>>>(d_in[4], d_out, ws);
}

// Round 7
// 176.858 us; speedup vs baseline: 2.5450x; 1.0700x over previous
//
#include <hip/hip_runtime.h>
#include <hip/hip_bf16.h>

#define SLOPE 0.1f

// ---- ws int-index layout: [0]=bf flag ----
// ---- ws float-index layout ----
#define OFF_QW    1816    // 30   q_weights (softmax)
#define OFF_QNI   1846    // 30   1/||question_embeds[q]||
#define OFF_QNS   1876    // 30   1/||q_conv[q]||
#define OFF_QNN   1906    // 30   ||question_embeds[q]|| (raw norm, for one-hot thr)
#define OFF_B1    4606    // 30
#define OFF_B2    7336    // 30
#define OFF_LQ1W  7366    // 48
#define OFF_LQ1B  7414    // 8
#define OFF_LQ2W  7422    // 8
#define OFF_LQ2B  7430    // 1
#define OFF_SOW   7431    // 4
#define OFF_SOB   7435    // 1
#define OFF_FLW   7436    // 5
#define OFF_FLB   7441    // 1
// ---- bf16 (u16-index) region, starts at byte 32768 ----
#define U16_QEA   16384   // 32 rows x 32  (A/B-operand QE, zeros at d>=30, q>=30)
#define U16_QCA   17408   // 32 rows x 32  (A/B-operand QC)
#define U16_WB1   18432   // 32 rows x 96  (B-operand conv1 W[o][kk], kk=k*30+i)
#define U16_WB2   21504   // 32 rows x 96

typedef __attribute__((ext_vector_type(8))) __bf16 bf16x8;
typedef __attribute__((ext_vector_type(4))) float f32x4;

union Frag { uint4 u4; uint u[4]; bf16x8 v; };

__device__ __forceinline__ float bf2f(ushort h) {
    union { uint u; float f; } c; c.u = ((uint)h) << 16; return c.f;
}
__device__ __forceinline__ ushort f2bf(float f) {   // RNE, finite inputs
    union { float f; uint u; } c; c.f = f;
    uint u = c.u;
    return (ushort)((u + 0x7FFFu + ((u >> 16) & 1u)) >> 16);
}
__device__ __forceinline__ float ldx(const void* p, long i, int bf) {
    if (bf) return bf2f(((const ushort*)p)[i]);
    return ((const float*)p)[i];
}
#define CE(x, y) { float _hi = fmaxf(x, y), _lo = fminf(x, y); x = _hi; y = _lo; }

__device__ __forceinline__ void sort4d(float& a, float& b, float& c, float& d) {
    CE(a, b); CE(c, d); CE(a, c); CE(b, d); CE(b, c);
}
// merge two sorted-desc 4-lists -> top5 desc
__device__ __forceinline__ void merge44_5(const float* a, const float* b, float* t) {
    t[0] = fmaxf(a[0], b[0]);
    t[1] = fmaxf(fminf(a[0], b[0]), fmaxf(a[1], b[1]));
    t[2] = fmaxf(fmaxf(fminf(a[0], b[1]), fminf(a[1], b[0])), fmaxf(a[2], b[2]));
    t[3] = fmaxf(fmaxf(fminf(a[0], b[2]), fminf(a[1], b[1])),
                 fmaxf(fminf(a[2], b[0]), fmaxf(a[3], b[3])));
    t[4] = fmaxf(fmaxf(fminf(a[0], b[3]), fminf(a[1], b[2])),
                 fmaxf(fminf(a[2], b[1]), fminf(a[3], b[0])));
}
// merge sorted5 + sorted4 -> top5
__device__ __forceinline__ void merge54_5(const float* a, const float* b, float* t) {
    t[0] = fmaxf(a[0], b[0]);
    t[1] = fmaxf(fminf(a[0], b[0]), fmaxf(a[1], b[1]));
    t[2] = fmaxf(fmaxf(fminf(a[0], b[1]), fminf(a[1], b[0])), fmaxf(a[2], b[2]));
    t[3] = fmaxf(fmaxf(fminf(a[0], b[2]), fminf(a[1], b[1])),
                 fmaxf(fminf(a[2], b[0]), fmaxf(a[3], b[3])));
    t[4] = fmaxf(fmaxf(fmaxf(fminf(a[0], b[3]), fminf(a[1], b[2])),
                       fmaxf(fminf(a[2], b[1]), fminf(a[3], b[0]))), a[4]);
}
// merge two sorted5 -> top5
__device__ __forceinline__ void merge55_5(const float* a, const float* b, float* t) {
    t[0] = fmaxf(a[0], b[0]);
    t[1] = fmaxf(fminf(a[0], b[0]), fmaxf(a[1], b[1]));
    t[2] = fmaxf(fmaxf(fminf(a[0], b[1]), fminf(a[1], b[0])), fmaxf(a[2], b[2]));
    t[3] = fmaxf(fmaxf(fminf(a[0], b[2]), fminf(a[1], b[1])),
                 fmaxf(fminf(a[2], b[0]), fmaxf(a[3], b[3])));
    t[4] = fmaxf(fmaxf(fmaxf(fminf(a[0], b[3]), fminf(a[1], b[2])),
                       fmaxf(fminf(a[2], b[1]), fminf(a[3], b[0]))),
                 fmaxf(a[4], b[4]));
}

// dtype detection: f32 mantissa words carry wild bf16-exponent fields
__device__ __forceinline__ int detect_bf(const void* doc_in, int tid, int* scnt) {
    if (tid == 0) *scnt = 0;
    __syncthreads();
    const ushort* p = (const ushort*)doc_in;
    int local = 0;
    for (int i = tid; i < 4096; i += 256) {
        unsigned e = (p[i] >> 7) & 0xFFu;
        if (e != 0u && (e < 100u || e > 134u)) local++;
    }
    atomicAdd(scnt, local);
    __syncthreads();
    return (*scnt > 200) ? 0 : 1;
}

// ---------------- kernel 1 (3 blocks): detect + question path + repack ----------------
__global__ __launch_bounds__(256) void k_prep(
        const void* doc_in,
        const void* qe_in, const void* qidf_in,
        const void* w1_in, const void* b1_in,
        const void* w2_in, const void* b2_in,
        const void* qwW_in, const void* qwb_in,
        const void* lq1W_in, const void* lq1b_in,
        const void* lq2W_in, const void* lq2b_in,
        const void* soW_in, const void* sob_in,
        const void* flW_in, const void* flb_in,
        float* ws) {
    const int tid = threadIdx.x;
    const int blk = blockIdx.x;
    __shared__ float QE[900], T1[900], QC[900], W[2700], IDF[32], LG[32];
    __shared__ int scnt;

    const int bf = detect_bf(doc_in, tid, &scnt);
    ushort* wsu = (ushort*)ws;

    if (blk == 1) {
        if (tid == 0) { ((int*)ws)[0] = bf; }
        if (tid < 30) ws[OFF_B1 + tid] = ldx(b1_in, tid, bf);
        if (tid < 48) ws[OFF_LQ1W + tid] = ldx(lq1W_in, tid, bf);
        if (tid < 8)  { ws[OFF_LQ1B + tid] = ldx(lq1b_in, tid, bf);
                        ws[OFF_LQ2W + tid] = ldx(lq2W_in, tid, bf); }
        if (tid < 4)  ws[OFF_SOW + tid] = ldx(soW_in, tid, bf);
        if (tid < 5)  ws[OFF_FLW + tid] = ldx(flW_in, tid, bf);
        if (tid == 1) { ws[OFF_LQ2B] = ldx(lq2b_in, 0, bf);
                        ws[OFF_SOB]  = ldx(sob_in, 0, bf);
                        ws[OFF_FLB]  = ldx(flb_in, 0, bf); }
        for (int i = tid; i < 3072; i += 256) {
            int o = i / 96, kk = i % 96;
            float v1 = 0.f;
            if (o < 30 && kk < 90) {
                int ii = kk % 30, k = kk / 30;
                v1 = ldx(w1_in, (long)o*90 + ii*3 + k, bf);
            }
            wsu[U16_WB1 + i] = f2bf(v1);
        }
        return;
    }
    if (blk == 2) {
        if (tid < 30) ws[OFF_B2 + tid] = ldx(b2_in, tid, bf);
        for (int i = tid; i < 3072; i += 256) {
            int o = i / 96, kk = i % 96;
            float v2 = 0.f;
            if (o < 30 && kk < 90) {
                int ii = kk % 30, k = kk / 30;
                v2 = ldx(w2_in, (long)o*90 + ii*3 + k, bf);
            }
            wsu[U16_WB2 + i] = f2bf(v2);
        }
        return;
    }

    // ---- block 0: control word + question path ----
    if (tid == 0) { ((int*)ws)[0] = bf; }

    for (int i = tid; i < 900; i += 256) QE[i] = ldx(qe_in, i, bf);
    if (tid < 30) IDF[tid] = ldx(qidf_in, tid, bf);
    for (int i = tid; i < 2700; i += 256) W[i] = ldx(w1_in, i, bf);
    __syncthreads();

    for (int idx = tid; idx < 900; idx += 256) {
        int s = idx / 30, o = idx % 30;
        float acc = ldx(b1_in, o, bf);
        for (int k = 0; k < 3; ++k) {
            int t = s + k - 1;
            if (t < 0 || t >= 30) continue;
            for (int i = 0; i < 30; ++i) acc += QE[t*30 + i] * W[o*90 + i*3 + k];
        }
        acc = acc >= 0.f ? acc : SLOPE * acc;
        T1[idx] = acc + QE[idx];
    }
    __syncthreads();
    for (int i = tid; i < 2700; i += 256) W[i] = ldx(w2_in, i, bf);
    __syncthreads();
    for (int idx = tid; idx < 900; idx += 256) {
        int s = idx / 30, o = idx % 30;
        float acc = ldx(b2_in, o, bf);
        for (int k = 0; k < 3; ++k) {
            int t = s + k - 1;
            if (t < 0 || t >= 30) continue;
            for (int i = 0; i < 30; ++i) acc += T1[t*30 + i] * W[o*90 + i*3 + k];
        }
        acc = acc >= 0.f ? acc : SLOPE * acc;
        QC[idx] = acc + T1[idx];
    }
    __syncthreads();

    if (tid < 30) {
        float s1 = 0.f, s2 = 0.f;
        for (int d = 0; d < 30; ++d) {
            float a = QE[tid*30 + d]; s1 += a*a;
            float b = QC[tid*30 + d]; s2 += b*b;
        }
        float n1 = sqrtf(s1);
        ws[OFF_QNN + tid] = n1;
        ws[OFF_QNI + tid] = 1.0f / n1;
        ws[OFF_QNS + tid] = 1.0f / sqrtf(s2);
        float z = ldx(qwb_in, 0, bf);
        for (int d = 0; d < 30; ++d) z += QC[tid*30 + d] * ldx(qwW_in, d, bf);
        z += IDF[tid] * ldx(qwW_in, 30, bf);
        LG[tid] = z;
    }
    __syncthreads();
    if (tid == 0) {
        float m = -1e30f;
        for (int q = 0; q < 30; ++q) m = fmaxf(m, LG[q]);
        float sum = 0.f, e[30];
        for (int q = 0; q < 30; ++q) { e[q] = expf(LG[q] - m); sum += e[q]; }
        for (int q = 0; q < 30; ++q) ws[OFF_QW + q] = e[q] / sum;
    }
    for (int i = tid; i < 1024; i += 256) {
        int q = i >> 5, d = i & 31;
        float ve = (q < 30 && d < 30) ? QE[q*30 + d] : 0.f;
        float vc = (q < 30 && d < 30) ? QC[q*30 + d] : 0.f;
        wsu[U16_QEA + i] = f2bf(ve);
        wsu[U16_QCA + i] = f2bf(vc);
    }
}

// ---------------- kernel 2: per-sentence fused MFMA pipeline ----------------
// block = 128 (2 waves). Sim GEMM is TRANSPOSED (A=X rows=s, B=Q^T cols=q):
// each lane owns one q and 28 in-register s-values -> in-lane top5 tournament
// + 2-step quad butterfly (vs 4x full-wave butterflies in the row layout).
__global__ __launch_bounds__(128, 4) void k_main(const void* doc_in, const void* gaf_in,
                                                 void* out, float* ws) {
    const int n = blockIdx.x;
    const int tid = threadIdx.x;
    const int bf = ((const int*)ws)[0];
    const int lane = tid & 63;
    const int wid = tid >> 6;          // 0 or 1
    const int l15 = lane & 15;
    const int quad = lane >> 4;

    __shared__ uint XA32[1546];        // X flat bf16: 103 rows x 30 (rows 0,101,102 zero)
    __shared__ uint XB32[1546];        // conv1 output, same layout
    __shared__ __align__(16) float INVX[112];   // [100,112) zero pad
    __shared__ float FE[30][6];
    __shared__ float IQI[32], IQS[32], QNN[32], BI1[32], BI2[32];

    ushort* XAu = (ushort*)XA32;
    const ushort* wsu = (const ushort*)ws;
    const uint4* qeA = (const uint4*)(wsu + U16_QEA);
    const uint4* qcA = (const uint4*)(wsu + U16_QCA);
    const uint4* wb1 = (const uint4*)(wsu + U16_WB1);
    const uint4* wb2 = (const uint4*)(wsu + U16_WB2);

    // prefetch gaf scalars (consumed at the very end by wave0 lane0)
    float ga0 = ldx(gaf_in, (long)n*3 + 0, bf);
    float ga1 = ldx(gaf_in, (long)n*3 + 1, bf);
    float ga2 = ldx(gaf_in, (long)n*3 + 2, bf);

    // ---- B0: zero pads, load sentence, cache small params in LDS ----
    for (int i = tid; i < 46; i += 128) {
        int j = (i < 15) ? i : (1500 + i);   // [0,15) and [1515,1546)
        XA32[j] = 0u; XB32[j] = 0u;
    }
    if (tid >= 100 && tid < 112) INVX[tid] = 0.f;
    if (bf) {
        const uint* g = (const uint*)((const ushort*)doc_in + (size_t)n * 3000);
        for (int i = tid; i < 1500; i += 128) XA32[15 + i] = g[i];
    } else {
        const float* p = (const float*)doc_in + (size_t)n * 3000;
        for (int i = tid; i < 3000; i += 128) XAu[30 + i] = f2bf(p[i]);
    }
    if (tid < 32) {
        IQI[tid] = ws[OFF_QNI + tid];
        IQS[tid] = ws[OFF_QNS + tid];
        QNN[tid] = ws[OFF_QNN + tid];
        BI1[tid] = ws[OFF_B1 + tid];
        BI2[tid] = ws[OFF_B2 + tid];
    }
    __syncthreads();

    // ---- B1: inverse row norms of X ----
    if (tid < 100) {
        const uint* r = XA32 + (tid + 1) * 15;
        float s = 0.f;
        #pragma unroll
        for (int i = 0; i < 15; ++i) {
            uint u = r[i];
            float lo = __uint_as_float(u << 16);
            float hi = __uint_as_float(u & 0xFFFF0000u);
            s += lo * lo + hi * hi;
        }
        INVX[tid] = 1.f / sqrtf(s);
    }
    __syncthreads();

    // transposed sim + in-lane pool; lane owns q = wid*16 + l15
    auto sim_pool = [&](const uint4* qa, const float* IQ, int fbase, bool do_oh) {
        const int q = wid * 16 + l15;
        Frag b;
        b.u4 = qa[q * 4 + quad];            // B[k=quad*8+j][n=q] == Q[q][k] table row
        f32x4 acc[7];
        #pragma unroll
        for (int mt = 0; mt < 7; ++mt) {
            int m = mt * 16 + l15;          // s-row of A
            Frag a;
            if (m < 100) {
                int base = (m + 1) * 15 + quad * 4;
                a.u[0] = XA32[base];     a.u[1] = XA32[base + 1];
                a.u[2] = XA32[base + 2]; a.u[3] = XA32[base + 3];
            } else { a.u[0] = a.u[1] = a.u[2] = a.u[3] = 0u; }
            f32x4 z = {0.f, 0.f, 0.f, 0.f};
            acc[mt] = __builtin_amdgcn_mfma_f32_16x16x32_bf16(a.v, b.v, z, 0, 0, 0);
        }
        // u[s] = num * invx[s]; s = mt*16 + quad*4 + r (in-lane)
        const float4* INVX4 = (const float4*)INVX;
        float thr = 0.999f * QNN[q];        // u > thr  <=>  sim > 0.999
        float iq  = (q < 30) ? IQ[q] : 0.f;
        float g[7][4];
        int cnt = 0;
        #pragma unroll
        for (int mt = 0; mt < 7; ++mt) {
            float4 ix = INVX4[mt * 4 + quad];
            float ixa[4] = {ix.x, ix.y, ix.z, ix.w};
            #pragma unroll
            for (int r = 0; r < 4; ++r) {
                float u = acc[mt][r] * ixa[r];
                if (mt == 6 && (quad * 4 + r) >= 4) u = -1e30f;   // s >= 100
                g[mt][r] = u;
                if (do_oh) cnt += (u > thr) ? 1 : 0;
            }
        }
        // in-lane top5-of-28: 7x sort4 + capped merge tree
        #pragma unroll
        for (int mt = 0; mt < 7; ++mt) sort4d(g[mt][0], g[mt][1], g[mt][2], g[mt][3]);
        float p0[5], p1[5], p2[5], q0[5], q1[5], t[5];
        merge44_5(g[0], g[1], p0);
        merge44_5(g[2], g[3], p1);
        merge44_5(g[4], g[5], p2);
        merge55_5(p0, p1, q0);
        merge54_5(p2, g[6], q1);
        merge55_5(q0, q1, t);
        // butterfly across the 4 quads (lanes xor 16, 32; l15 preserved)
        #pragma unroll
        for (int d = 16; d < 64; d <<= 1) {
            float pp[5];
            pp[0] = __shfl_xor(t[0], d); pp[1] = __shfl_xor(t[1], d);
            pp[2] = __shfl_xor(t[2], d); pp[3] = __shfl_xor(t[3], d);
            pp[4] = __shfl_xor(t[4], d);
            if (do_oh) cnt += __shfl_xor(cnt, d);
            float tn[5];
            merge55_5(t, pp, tn);
            t[0] = tn[0]; t[1] = tn[1]; t[2] = tn[2]; t[3] = tn[3]; t[4] = tn[4];
        }
        if (quad == 0 && q < 30) {
            if (do_oh) {
                FE[q][0] = cnt > 0 ? 1.f : 0.f;
                FE[q][1] = (float)(cnt > 5 ? 5 : cnt) * 0.2f;
            }
            FE[q][fbase]     = t[0] * iq;
            FE[q][fbase + 1] = (t[0] + t[1] + t[2] + t[3] + t[4]) * 0.2f * iq;
        }
    };

    // conv for one mt; A-fragments shared across nt tiles [nt0, nt1]
    auto conv_mt = [&](const uint* src32, uint* dst32, const uint4* wb,
                       const float* bias, int mt, int nt0, int nt1) {
        const ushort* srcU = (const ushort*)src32;
        ushort* dstU = (ushort*)dst32;
        int sa = mt * 16 + l15;
        Frag a[3];
        #pragma unroll
        for (int k = 0; k < 3; ++k) {
            if (sa < 100) {
                int base = sa * 15 + k * 16 + quad * 4;
                a[k].u[0] = src32[base];     a[k].u[1] = src32[base + 1];
                a[k].u[2] = src32[base + 2]; a[k].u[3] = src32[base + 3];
            } else { a[k].u[0] = a[k].u[1] = a[k].u[2] = a[k].u[3] = 0u; }
        }
        for (int nt = nt0; nt <= nt1; ++nt) {
            f32x4 acc = {0.f, 0.f, 0.f, 0.f};
            #pragma unroll
            for (int k = 0; k < 3; ++k) {
                Frag b;
                b.u4 = wb[(nt * 16 + l15) * 12 + k * 4 + quad];
                acc = __builtin_amdgcn_mfma_f32_16x16x32_bf16(a[k].v, b.v, acc, 0, 0, 0);
            }
            int o = nt * 16 + l15;
            if (o < 30) {
                float bo = bias[o];
                #pragma unroll
                for (int r = 0; r < 4; ++r) {
                    int s = mt * 16 + quad * 4 + r;
                    if (s < 100) {
                        float v = acc[r] + bo;
                        v = v >= 0.f ? v : SLOPE * v;
                        v += bf2f(srcU[(s + 1) * 30 + o]);
                        dstU[(s + 1) * 30 + o] = f2bf(v);
                    }
                }
            }
        }
    };

    // ---- B2: sim_insens + pool (registers) then conv1 XA->XB ----
    sim_pool(qeA, IQI, 2, true);
    conv_mt(XA32, XB32, wb1, BI1, wid,     0, 1);
    conv_mt(XA32, XB32, wb1, BI1, wid + 2, 0, 1);
    conv_mt(XA32, XB32, wb1, BI1, wid + 4, 0, 1);
    conv_mt(XA32, XB32, wb1, BI1, 6,       wid, wid);
    __syncthreads();

    // ---- B3: conv2 XB->XA ----
    conv_mt(XB32, XA32, wb2, BI2, wid,     0, 1);
    conv_mt(XB32, XA32, wb2, BI2, wid + 2, 0, 1);
    conv_mt(XB32, XA32, wb2, BI2, wid + 4, 0, 1);
    conv_mt(XB32, XA32, wb2, BI2, 6,       wid, wid);
    __syncthreads();

    // ---- B4: inverse row norms of conv_res ----
    if (tid < 100) {
        const uint* r = XA32 + (tid + 1) * 15;
        float s = 0.f;
        #pragma unroll
        for (int i = 0; i < 15; ++i) {
            uint u = r[i];
            float lo = __uint_as_float(u << 16);
            float hi = __uint_as_float(u & 0xFFFF0000u);
            s += lo * lo + hi * hi;
        }
        INVX[tid] = 1.f / sqrtf(s);
    }
    __syncthreads();

    // ---- B5: sim_sens + pool (registers) ----
    sim_pool(qcA, IQS, 4, false);
    __syncthreads();

    // ---- B6: wave0: per-q MLP, butterfly-sum, score write ----
    if (wid == 0) {
        float val = 0.f;
        if (lane < 30) {
            float lo = ws[OFF_LQ2B];
            #pragma unroll
            for (int j = 0; j < 8; ++j) {
                float h = ws[OFF_LQ1B + j];
                #pragma unroll
                for (int f = 0; f < 6; ++f) h += FE[lane][f] * ws[OFF_LQ1W + j*6 + f];
                h = h >= 0.f ? h : SLOPE * h;
                lo += h * ws[OFF_LQ2W + j];
            }
            val = lo * ws[OFF_QW + lane];
        }
        for (int d = 32; d >= 1; d >>= 1) val += __shfl_xor(val, d);
        if (lane == 0) {
            float emit = val * (1.f / 30.f);
            float z = ws[OFF_SOB];
            z += ga0 * ws[OFF_SOW + 0];
            z += ga1 * ws[OFF_SOW + 1];
            z += ga2 * ws[OFF_SOW + 2];
            z += emit * ws[OFF_SOW + 3];
            float sc = 1.f / (1.f + expf(-z));
            if (bf) ((__hip_bfloat16*)out)[1 + n] = __float2bfloat16(sc);
            else    ((float*)out)[1 + n] = sc;
        }
    }
}

// ---------------- kernel 3: doc-level head ----------------
__global__ __launch_bounds__(256) void k_final(const void* docgaf_in, void* out, const float* ws) {
    const int tid = threadIdx.x;
    const int bf = ((const int*)ws)[0];
    __shared__ float red[256];
    float m = -1e30f;
    for (int i = tid; i < 4000; i += 256) {
        float v = bf ? __bfloat162float(((const __hip_bfloat16*)out)[1 + i])
                     : ((const float*)out)[1 + i];
        m = fmaxf(m, v);
    }
    red[tid] = m;
    __syncthreads();
    for (int off = 128; off > 0; off >>= 1) {
        if (tid < off) red[tid] = fmaxf(red[tid], red[tid + off]);
        __syncthreads();
    }
    if (tid == 0) {
        float f = ws[OFF_FLB] + red[0] * ws[OFF_FLW + 0];
        for (int i = 0; i < 4; ++i) f += ldx(docgaf_in, i, bf) * ws[OFF_FLW + 1 + i];
        if (bf) ((__hip_bfloat16*)out)[0] = __float2bfloat16(f);
        else    ((float*)out)[0] = f;
    }
}

extern "C" void kernel_launch(void* const* d_in, const int* in_sizes, int n_in,
                              void* d_out, int out_size, void* d_ws, size_t ws_size,
                              hipStream_t stream) {
    float* ws = (float*)d_ws;
    k_prep<<<3, 256, 0, stream>>>(d_in[0], d_in[2], d_in[3], d_in[5], d_in[6], d_in[7], d_in[8],
                                  d_in[9], d_in[10], d_in[11], d_in[12], d_in[13], d_in[14],
                                  d_in[15], d_in[16], d_in[17], d_in[18], ws);
    k_main<<<4000, 128, 0, stream>>>(d_in[0], d_in[1], d_out, ws);
    k_final<<<1, 256, 0, stream>>>(d_in[4], d_out, ws);
}